// Round 3
// baseline (948.899 us; speedup 1.0000x reference)
//
#include <hip/hip_runtime.h>
#include <hip/hip_bf16.h>
#include <cstdint>

typedef _Float16 f16x8 __attribute__((ext_vector_type(8)));
typedef _Float16 f16x4 __attribute__((ext_vector_type(4)));
typedef float    f32x4 __attribute__((ext_vector_type(4)));

static constexpr int B = 8, S = 2048, D = 1024;
static constexpr long BSD = (long)B * S * D;   // 16,777,216
static constexpr long SD  = (long)S * D;       // 2,097,152
static constexpr long SS  = (long)S * S;       // 4,194,304
static constexpr long DD  = (long)D * D;       // 1,048,576

__device__ __forceinline__ void gload16(const void* g, void* l) {
  __builtin_amdgcn_global_load_lds(
      (const __attribute__((address_space(1))) void*)g,
      (__attribute__((address_space(3))) void*)l, 16, 0, 0);
}

// ---------------- prep: xp = x + pos -> f16 ----------------
__global__ __launch_bounds__(256) void prep_x_kernel(
    const float* __restrict__ x, const float* __restrict__ pos,
    _Float16* __restrict__ xh) {
  long i = ((long)blockIdx.x * 256 + threadIdx.x) * 4;
  float4 xv = *(const float4*)(x + i);
  long p = i & (SD - 1);
  float4 pv = *(const float4*)(pos + p);
  f16x4 h;
  h.x = (_Float16)(xv.x + pv.x);
  h.y = (_Float16)(xv.y + pv.y);
  h.z = (_Float16)(xv.z + pv.z);
  h.w = (_Float16)(xv.w + pv.w);
  *(f16x4*)(xh + i) = h;
}

// ---------------- prep: weights -> transposed f16, LDS-tiled (coalesced) ----------------
__global__ __launch_bounds__(256) void prep_w_kernel(
    const float* __restrict__ Wq, const float* __restrict__ Wk,
    const float* __restrict__ Wv, const float* __restrict__ Wo,
    _Float16* __restrict__ wqkv, _Float16* __restrict__ woh) {
  __shared__ _Float16 t[64][65];
  const int c0 = blockIdx.x * 64;   // original col block (= output row block)
  const int r0 = blockIdx.y * 64;   // original row block (= output col block)
  const int tid = threadIdx.x;
  const int lc = tid & 63;
  const int lr4 = tid >> 6;         // 0..3
  const float* srcs[4] = {Wq, Wk, Wv, Wo};
  #pragma unroll
  for (int m = 0; m < 4; ++m) {
    const float* src = srcs[m];
    _Float16* dst = (m < 3) ? (wqkv + (long)m * DD) : woh;
    #pragma unroll
    for (int ii = 0; ii < 16; ++ii) {
      int row = ii * 4 + lr4;
      t[lc][row] = (_Float16)src[(long)(r0 + row) * D + c0 + lc];
    }
    __syncthreads();
    #pragma unroll
    for (int ii = 0; ii < 16; ++ii) {
      int orow = ii * 4 + lr4;
      dst[(long)(c0 + orow) * D + r0 + lc] = t[orow][lc];
    }
    __syncthreads();
  }
}

// ---------------- prep: bias concat + pw table ----------------
__global__ __launch_bounds__(256) void prep_misc_kernel(
    const float* __restrict__ bq, const float* __restrict__ bk,
    const float* __restrict__ bv,
    float* __restrict__ bcat, float* __restrict__ pwtab) {
  int i = blockIdx.x * 256 + threadIdx.x;   // grid 20 blocks -> i < 5120
  if (i < 3072) {
    float v = (i < 1024) ? bq[i] : (i < 2048) ? bk[i - 1024] : bv[i - 2048];
    bcat[i] = v;
  }
  int d = i - 3072;
  if (d >= 0 && d < 2048) {
    float dist = (float)d * (1.0f / 2048.0f);
    pwtab[d] = (1.0f + 1.5f * expf(-2.0f * dist)) * (1.0f / 2.5f) * (1.0f / 32.0f);
  }
}

// ---------------- generic MFMA GEMM: C[M,N] = A[M,K] * Bt[N,K]^T ----------------
enum { EPI_QKV = 0, EPI_SF16 = 1, EPI_PVO = 2, EPI_F32B = 3 };

template<int EPI>
__global__ __launch_bounds__(256, 5) void gemm_kernel(
    const _Float16* __restrict__ A, const _Float16* __restrict__ Bt,
    const float* __restrict__ bias, const float* __restrict__ pwtab,
    float* __restrict__ outF,
    _Float16* __restrict__ o0, _Float16* __restrict__ o1, _Float16* __restrict__ o2,
    int M, int N, int K, long sA, long sB, long sC)
{
  constexpr int BM = 128, BN = 128, BK = 64;
  __shared__ __align__(16) _Float16 smem[2 * BM * BK];
  _Float16* Ash = smem;
  _Float16* Bsh = smem + BM * BK;

  const int tid = threadIdx.x;
  const int z = blockIdx.z;
  const long arow0 = (long)blockIdx.y * BM;
  const long brow0 = (long)blockIdx.x * BN;
  const _Float16* Ag = A + (long)z * sA + arow0 * K;
  const _Float16* Bg = Bt + (long)z * sB + brow0 * K;

  const int lane = tid & 63;
  const int wr = ((tid >> 6) >> 1) * 64;   // wave row offset in tile
  const int wc = ((tid >> 6) & 1) * 64;    // wave col offset
  const int lrow = lane & 15;
  const int lk = (lane >> 4) * 8;

  f32x4 acc[4][4] = {};

  for (int k0 = 0; k0 < K; k0 += BK) {
    #pragma unroll
    for (int rr = 0; rr < 4; ++rr) {
      const int chunk = rr * 256 + tid;     // 0..1023
      const int row = chunk >> 3;           // 0..127
      const int col = (chunk & 7) * 8;      // 0..56
      gload16(Ag + (long)row * K + k0 + col, Ash + chunk * 8);
      gload16(Bg + (long)row * K + k0 + col, Bsh + chunk * 8);
    }
    __syncthreads();
    #pragma unroll
    for (int kk = 0; kk < 2; ++kk) {
      f16x8 a_h[4];
      #pragma unroll
      for (int i = 0; i < 4; ++i)
        a_h[i] = *(const f16x8*)&Ash[(wr + i * 16 + lrow) * BK + kk * 32 + lk];
      #pragma unroll
      for (int j = 0; j < 4; ++j) {
        const f16x8 b_h = *(const f16x8*)&Bsh[(wc + j * 16 + lrow) * BK + kk * 32 + lk];
        #pragma unroll
        for (int i = 0; i < 4; ++i)
          acc[i][j] = __builtin_amdgcn_mfma_f32_16x16x32_f16(a_h[i], b_h, acc[i][j], 0, 0, 0);
      }
    }
    __syncthreads();
  }

  // epilogue: C/D layout col = lane&15, row = (lane>>4)*4 + r  [m89-verified]
  const int rbase = (int)arow0 + wr + (lane >> 4) * 4;
  const int cbase = (int)brow0 + wc + lrow;

  if (EPI == EPI_QKV) {
    // block-uniform routing: matrix id from the N-block (N=3072 = Q|K|V)
    const int matid = (int)(brow0 >> 10);
    _Float16* dst = (matid == 0) ? o0 : (matid == 1) ? o1 : o2;
    #pragma unroll
    for (int j = 0; j < 4; ++j) {
      const int col = cbase + j * 16;
      const float bv = bias[col];
      const int cl = col & 1023;
      #pragma unroll
      for (int i = 0; i < 4; ++i) {
        #pragma unroll
        for (int r = 0; r < 4; ++r) {
          const int row = rbase + i * 16 + r;
          const float v = acc[i][j][r] + bv;
          if (matid < 2) {
            dst[(long)row * 1024 + cl] = (_Float16)v;
          } else {
            const int bb = row >> 11;
            const int t = row & (S - 1);
            dst[(long)bb * SD + (long)cl * S + t] = (_Float16)v;
          }
        }
      }
    }
  } else if (EPI == EPI_SF16) {
    #pragma unroll
    for (int j = 0; j < 4; ++j) {
      const int col = cbase + j * 16;
      #pragma unroll
      for (int i = 0; i < 4; ++i) {
        #pragma unroll
        for (int r = 0; r < 4; ++r) {
          const int row = rbase + i * 16 + r;
          int dd = row - col; if (dd < 0) dd = -dd;
          const float v = acc[i][j][r] * pwtab[dd];
          o0[(long)z * sC + (long)row * N + col] = (_Float16)v;
        }
      }
    }
  } else if (EPI == EPI_PVO) {
    #pragma unroll
    for (int j = 0; j < 4; ++j) {
      const int col = cbase + j * 16;
      #pragma unroll
      for (int i = 0; i < 4; ++i) {
        #pragma unroll
        for (int r = 0; r < 4; ++r) {
          const int row = rbase + i * 16 + r;
          o0[(long)z * sC + (long)row * N + col] = (_Float16)acc[i][j][r];
        }
      }
    }
  } else {  // EPI_F32B
    #pragma unroll
    for (int j = 0; j < 4; ++j) {
      const int col = cbase + j * 16;
      const float bv = bias[col];
      #pragma unroll
      for (int i = 0; i < 4; ++i) {
        #pragma unroll
        for (int r = 0; r < 4; ++r) {
          const int row = rbase + i * 16 + r;
          outF[(long)row * N + col] = acc[i][j][r] + bv;
        }
      }
    }
  }
}

// ---------------- row softmax over 2048: f16 in -> f32 attn + f16 copy ----------------
__global__ __launch_bounds__(256) void softmax_kernel(
    const _Float16* __restrict__ sbf, float* __restrict__ attn,
    _Float16* __restrict__ abf) {
  const long base = (long)blockIdx.x * S + threadIdx.x * 8;
  const int tid = threadIdx.x;
  const f16x8 sv = *(const f16x8*)(sbf + base);
  float v[8];
  #pragma unroll
  for (int t = 0; t < 8; ++t) v[t] = (float)sv[t];
  float m = fmaxf(fmaxf(fmaxf(v[0], v[1]), fmaxf(v[2], v[3])),
                  fmaxf(fmaxf(v[4], v[5]), fmaxf(v[6], v[7])));
  #pragma unroll
  for (int sh = 1; sh < 64; sh <<= 1) m = fmaxf(m, __shfl_xor(m, sh));
  __shared__ float red[8];
  const int w = tid >> 6;
  if ((tid & 63) == 0) red[w] = m;
  __syncthreads();
  m = fmaxf(fmaxf(red[0], red[1]), fmaxf(red[2], red[3]));
  float e[8];
  #pragma unroll
  for (int t = 0; t < 8; ++t) e[t] = expf(v[t] - m);
  float s8 = ((e[0] + e[1]) + (e[2] + e[3])) + ((e[4] + e[5]) + (e[6] + e[7]));
  #pragma unroll
  for (int sh = 1; sh < 64; sh <<= 1) s8 += __shfl_xor(s8, sh);
  if ((tid & 63) == 0) red[4 + w] = s8;
  __syncthreads();
  const float inv = 1.0f / ((red[4] + red[5]) + (red[6] + red[7]));
  float4 o0 = make_float4(e[0] * inv, e[1] * inv, e[2] * inv, e[3] * inv);
  float4 o1 = make_float4(e[4] * inv, e[5] * inv, e[6] * inv, e[7] * inv);
  *(float4*)(attn + base) = o0;
  *(float4*)(attn + base + 4) = o1;
  f16x8 hb;
  hb[0] = (_Float16)o0.x; hb[1] = (_Float16)o0.y;
  hb[2] = (_Float16)o0.z; hb[3] = (_Float16)o0.w;
  hb[4] = (_Float16)o1.x; hb[5] = (_Float16)o1.y;
  hb[6] = (_Float16)o1.z; hb[7] = (_Float16)o1.w;
  *(f16x8*)(abf + base) = hb;
}

extern "C" void kernel_launch(void* const* d_in, const int* in_sizes, int n_in,
                              void* d_out, int out_size, void* d_ws, size_t ws_size,
                              hipStream_t stream) {
  const float* x   = (const float*)d_in[0];
  const float* pos = (const float*)d_in[1];
  const float* Wq  = (const float*)d_in[2];
  const float* bq  = (const float*)d_in[3];
  const float* Wk  = (const float*)d_in[4];
  const float* bk  = (const float*)d_in[5];
  const float* Wv  = (const float*)d_in[6];
  const float* bv  = (const float*)d_in[7];
  const float* Wo  = (const float*)d_in[8];
  const float* bo  = (const float*)d_in[9];

  float* outp  = (float*)d_out;          // [B,S,D] f32
  float* attnp = outp + BSD;             // [B,S,S] f32 (final attn)

  // workspace layout (~176 MB of the ~768 MB ws)
  _Float16* wqkv = (_Float16*)d_ws;              // [3072][1024] f16 (6 MB)
  _Float16* woh  = wqkv + 3 * DD;                // [1024][1024] f16 (2 MB)
  float*    bcat = (float*)(woh + DD);           // [3072] f32
  float*    pwtab = bcat + 3072;                 // [2048] f32
  _Float16* qh  = (_Float16*)(pwtab + 2048);     // [B*S][D] f16 (33.5 MB)
  _Float16* kh  = qh + BSD;                      // [B*S][D]
  _Float16* vt  = kh + BSD;                      // [B][D][S]
  _Float16* sbf = vt + BSD;                      // [B][S][S] f16 scores (67 MB)
  _Float16* abf = sbf + (long)B * SS;            // [B][S][S] f16 attn (67 MB)
  _Float16* hbf = qh;                            // PV out reuses qh (dead after scores)

  // xp f16 lives in the (not-yet-written) attn region of d_out
  _Float16* xph = (_Float16*)attnp;

  dim3 blk(256);
  prep_w_kernel<<<dim3(16, 16), blk, 0, stream>>>(Wq, Wk, Wv, Wo, wqkv, woh);
  prep_misc_kernel<<<dim3(20), blk, 0, stream>>>(bq, bk, bv, bcat, pwtab);
  prep_x_kernel<<<dim3((int)(BSD / 1024)), blk, 0, stream>>>(x, pos, xph);

  // fused QKV projection: [16384,1024] @ [3072,1024]^T
  dim3 gQKV(3 * D / 128, (B * S) / 128, 1);   // (24,128,1)
  gemm_kernel<EPI_QKV><<<gQKV, blk, 0, stream>>>(
      xph, wqkv, bcat, nullptr, nullptr, qh, kh, vt, B * S, 3 * D, D, 0, 0, 0);

  // scores (f16, pw-scaled): per-batch [2048,1024] @ [2048,1024]^T
  dim3 gScore(S / 128, S / 128, B);           // (16,16,8)
  gemm_kernel<EPI_SF16><<<gScore, blk, 0, stream>>>(
      qh, kh, nullptr, pwtab, nullptr, sbf, nullptr, nullptr, S, S, D, SD, SD, SS);

  softmax_kernel<<<dim3(B * S), blk, 0, stream>>>(sbf, attnp, abf);

  // PV: per-batch [2048,2048] @ [1024,2048]^T
  dim3 gPV(D / 128, S / 128, B);              // (8,16,8)
  gemm_kernel<EPI_PVO><<<gPV, blk, 0, stream>>>(
      abf, vt, nullptr, nullptr, nullptr, hbf, nullptr, nullptr, S, D, S, SS, SD, SD);

  // out-proj: [16384,1024] @ [1024,1024]^T + bo -> f32
  dim3 gOut(D / 128, (B * S) / 128, 1);       // (8,128,1)
  gemm_kernel<EPI_F32B><<<gOut, blk, 0, stream>>>(
      hbf, woh, bo, nullptr, outp, nullptr, nullptr, nullptr, B * S, D, D, 0, 0, 0);
}

// Round 4
// 490.995 us; speedup vs baseline: 1.9326x; 1.9326x over previous
//
#include <hip/hip_runtime.h>
#include <hip/hip_bf16.h>
#include <cstdint>

typedef _Float16 f16x8 __attribute__((ext_vector_type(8)));
typedef _Float16 f16x4 __attribute__((ext_vector_type(4)));
typedef float    f32x4 __attribute__((ext_vector_type(4)));

static constexpr int B = 8, S = 2048, D = 1024;
static constexpr long BSD = (long)B * S * D;   // 16,777,216
static constexpr long SD  = (long)S * D;       // 2,097,152
static constexpr long SS  = (long)S * S;       // 4,194,304
static constexpr long DD  = (long)D * D;       // 1,048,576

__device__ __forceinline__ void gload16(const void* g, void* l) {
  __builtin_amdgcn_global_load_lds(
      (const __attribute__((address_space(1))) void*)g,
      (__attribute__((address_space(3))) void*)l, 16, 0, 0);
}

// ---------------- prep: xp = x + pos -> f16 ----------------
__global__ __launch_bounds__(256) void prep_x_kernel(
    const float* __restrict__ x, const float* __restrict__ pos,
    _Float16* __restrict__ xh) {
  long i = ((long)blockIdx.x * 256 + threadIdx.x) * 4;
  float4 xv = *(const float4*)(x + i);
  long p = i & (SD - 1);
  float4 pv = *(const float4*)(pos + p);
  f16x4 h;
  h.x = (_Float16)(xv.x + pv.x);
  h.y = (_Float16)(xv.y + pv.y);
  h.z = (_Float16)(xv.z + pv.z);
  h.w = (_Float16)(xv.w + pv.w);
  *(f16x4*)(xh + i) = h;
}

// ---------------- prep: weights -> transposed f16, LDS-tiled (coalesced) ----------------
__global__ __launch_bounds__(256) void prep_w_kernel(
    const float* __restrict__ Wq, const float* __restrict__ Wk,
    const float* __restrict__ Wv, const float* __restrict__ Wo,
    _Float16* __restrict__ wqkv, _Float16* __restrict__ woh) {
  __shared__ _Float16 t[64][65];
  const int c0 = blockIdx.x * 64;   // original col block (= output row block)
  const int r0 = blockIdx.y * 64;   // original row block (= output col block)
  const int tid = threadIdx.x;
  const int lc = tid & 63;
  const int lr4 = tid >> 6;         // 0..3
  const float* srcs[4] = {Wq, Wk, Wv, Wo};
  #pragma unroll
  for (int m = 0; m < 4; ++m) {
    const float* src = srcs[m];
    _Float16* dst = (m < 3) ? (wqkv + (long)m * DD) : woh;
    #pragma unroll
    for (int ii = 0; ii < 16; ++ii) {
      int row = ii * 4 + lr4;
      t[lc][row] = (_Float16)src[(long)(r0 + row) * D + c0 + lc];
    }
    __syncthreads();
    #pragma unroll
    for (int ii = 0; ii < 16; ++ii) {
      int orow = ii * 4 + lr4;
      dst[(long)(c0 + orow) * D + r0 + lc] = t[orow][lc];
    }
    __syncthreads();
  }
}

// ---------------- prep: bias concat + pw table ----------------
__global__ __launch_bounds__(256) void prep_misc_kernel(
    const float* __restrict__ bq, const float* __restrict__ bk,
    const float* __restrict__ bv,
    float* __restrict__ bcat, float* __restrict__ pwtab) {
  int i = blockIdx.x * 256 + threadIdx.x;   // grid 20 blocks -> i < 5120
  if (i < 3072) {
    float v = (i < 1024) ? bq[i] : (i < 2048) ? bk[i - 1024] : bv[i - 2048];
    bcat[i] = v;
  }
  int d = i - 3072;
  if (d >= 0 && d < 2048) {
    float dist = (float)d * (1.0f / 2048.0f);
    pwtab[d] = (1.0f + 1.5f * expf(-2.0f * dist)) * (1.0f / 2.5f) * (1.0f / 32.0f);
  }
}

// ---------------- generic MFMA GEMM: C[M,N] = A[M,K] * Bt[N,K]^T ----------------
enum { EPI_QKV = 0, EPI_SF16 = 1, EPI_PVO = 2, EPI_F32B = 3 };

template<int EPI>
__global__ __launch_bounds__(256, 4) void gemm_kernel(
    const _Float16* __restrict__ A, const _Float16* __restrict__ Bt,
    const float* __restrict__ bias, const float* __restrict__ pwtab,
    float* __restrict__ outF,
    _Float16* __restrict__ o0, _Float16* __restrict__ o1, _Float16* __restrict__ o2,
    int M, int N, int K, long sA, long sB, long sC)
{
  constexpr int BM = 128, BN = 128, BK = 64;
  __shared__ __align__(16) _Float16 smem[2 * BM * BK];
  _Float16* Ash = smem;
  _Float16* Bsh = smem + BM * BK;

  const int tid = threadIdx.x;
  const int z = blockIdx.z;
  const long arow0 = (long)blockIdx.y * BM;
  const long brow0 = (long)blockIdx.x * BN;
  const _Float16* Ag = A + (long)z * sA + arow0 * K;
  const _Float16* Bg = Bt + (long)z * sB + brow0 * K;

  const int lane = tid & 63;
  const int wr = ((tid >> 6) >> 1) * 64;   // wave row offset in tile
  const int wc = ((tid >> 6) & 1) * 64;    // wave col offset
  const int lrow = lane & 15;
  const int lk = (lane >> 4) * 8;

  f32x4 acc[4][4] = {};

  for (int k0 = 0; k0 < K; k0 += BK) {
    #pragma unroll
    for (int rr = 0; rr < 4; ++rr) {
      const int chunk = rr * 256 + tid;     // 0..1023
      const int row = chunk >> 3;           // 0..127
      const int col = (chunk & 7) * 8;      // 0..56
      gload16(Ag + (long)row * K + k0 + col, Ash + chunk * 8);
      gload16(Bg + (long)row * K + k0 + col, Bsh + chunk * 8);
    }
    __syncthreads();
    #pragma unroll
    for (int kk = 0; kk < 2; ++kk) {
      f16x8 a_h[4];
      #pragma unroll
      for (int i = 0; i < 4; ++i)
        a_h[i] = *(const f16x8*)&Ash[(wr + i * 16 + lrow) * BK + kk * 32 + lk];
      #pragma unroll
      for (int j = 0; j < 4; ++j) {
        const f16x8 b_h = *(const f16x8*)&Bsh[(wc + j * 16 + lrow) * BK + kk * 32 + lk];
        #pragma unroll
        for (int i = 0; i < 4; ++i)
          acc[i][j] = __builtin_amdgcn_mfma_f32_16x16x32_f16(a_h[i], b_h, acc[i][j], 0, 0, 0);
      }
    }
    __syncthreads();
  }

  // epilogue: C/D layout col = lane&15, row = (lane>>4)*4 + r  [m89-verified]
  const int rbase = (int)arow0 + wr + (lane >> 4) * 4;
  const int cbase = (int)brow0 + wc + lrow;

  if (EPI == EPI_QKV) {
    // block-uniform routing: matrix id from the N-block (N=3072 = Q|K|V)
    const int matid = (int)(brow0 >> 10);
    _Float16* dst = (matid == 0) ? o0 : (matid == 1) ? o1 : o2;
    #pragma unroll
    for (int j = 0; j < 4; ++j) {
      const int col = cbase + j * 16;
      const float bv = bias[col];
      const int cl = col & 1023;
      #pragma unroll
      for (int i = 0; i < 4; ++i) {
        #pragma unroll
        for (int r = 0; r < 4; ++r) {
          const int row = rbase + i * 16 + r;
          const float v = acc[i][j][r] + bv;
          if (matid < 2) {
            dst[(long)row * 1024 + cl] = (_Float16)v;
          } else {
            const int bb = row >> 11;
            const int t = row & (S - 1);
            dst[(long)bb * SD + (long)cl * S + t] = (_Float16)v;
          }
        }
      }
    }
  } else if (EPI == EPI_SF16) {
    #pragma unroll
    for (int j = 0; j < 4; ++j) {
      const int col = cbase + j * 16;
      #pragma unroll
      for (int i = 0; i < 4; ++i) {
        #pragma unroll
        for (int r = 0; r < 4; ++r) {
          const int row = rbase + i * 16 + r;
          int dd = row - col; if (dd < 0) dd = -dd;
          const float v = acc[i][j][r] * pwtab[dd];
          o0[(long)z * sC + (long)row * N + col] = (_Float16)v;
        }
      }
    }
  } else if (EPI == EPI_PVO) {
    #pragma unroll
    for (int j = 0; j < 4; ++j) {
      const int col = cbase + j * 16;
      #pragma unroll
      for (int i = 0; i < 4; ++i) {
        #pragma unroll
        for (int r = 0; r < 4; ++r) {
          const int row = rbase + i * 16 + r;
          o0[(long)z * sC + (long)row * N + col] = (_Float16)acc[i][j][r];
        }
      }
    }
  } else {  // EPI_F32B
    #pragma unroll
    for (int j = 0; j < 4; ++j) {
      const int col = cbase + j * 16;
      const float bv = bias[col];
      #pragma unroll
      for (int i = 0; i < 4; ++i) {
        #pragma unroll
        for (int r = 0; r < 4; ++r) {
          const int row = rbase + i * 16 + r;
          outF[(long)row * N + col] = acc[i][j][r] + bv;
        }
      }
    }
  }
}

// ---------------- row softmax over 2048: f16 in -> f32 attn + f16 copy ----------------
__global__ __launch_bounds__(256) void softmax_kernel(
    const _Float16* __restrict__ sbf, float* __restrict__ attn,
    _Float16* __restrict__ abf) {
  const long base = (long)blockIdx.x * S + threadIdx.x * 8;
  const int tid = threadIdx.x;
  const f16x8 sv = *(const f16x8*)(sbf + base);
  float v[8];
  #pragma unroll
  for (int t = 0; t < 8; ++t) v[t] = (float)sv[t];
  float m = fmaxf(fmaxf(fmaxf(v[0], v[1]), fmaxf(v[2], v[3])),
                  fmaxf(fmaxf(v[4], v[5]), fmaxf(v[6], v[7])));
  #pragma unroll
  for (int sh = 1; sh < 64; sh <<= 1) m = fmaxf(m, __shfl_xor(m, sh));
  __shared__ float red[8];
  const int w = tid >> 6;
  if ((tid & 63) == 0) red[w] = m;
  __syncthreads();
  m = fmaxf(fmaxf(red[0], red[1]), fmaxf(red[2], red[3]));
  float e[8];
  #pragma unroll
  for (int t = 0; t < 8; ++t) e[t] = expf(v[t] - m);
  float s8 = ((e[0] + e[1]) + (e[2] + e[3])) + ((e[4] + e[5]) + (e[6] + e[7]));
  #pragma unroll
  for (int sh = 1; sh < 64; sh <<= 1) s8 += __shfl_xor(s8, sh);
  if ((tid & 63) == 0) red[4 + w] = s8;
  __syncthreads();
  const float inv = 1.0f / ((red[4] + red[5]) + (red[6] + red[7]));
  float4 o0 = make_float4(e[0] * inv, e[1] * inv, e[2] * inv, e[3] * inv);
  float4 o1 = make_float4(e[4] * inv, e[5] * inv, e[6] * inv, e[7] * inv);
  *(float4*)(attn + base) = o0;
  *(float4*)(attn + base + 4) = o1;
  f16x8 hb;
  hb[0] = (_Float16)o0.x; hb[1] = (_Float16)o0.y;
  hb[2] = (_Float16)o0.z; hb[3] = (_Float16)o0.w;
  hb[4] = (_Float16)o1.x; hb[5] = (_Float16)o1.y;
  hb[6] = (_Float16)o1.z; hb[7] = (_Float16)o1.w;
  *(f16x8*)(abf + base) = hb;
}

extern "C" void kernel_launch(void* const* d_in, const int* in_sizes, int n_in,
                              void* d_out, int out_size, void* d_ws, size_t ws_size,
                              hipStream_t stream) {
  const float* x   = (const float*)d_in[0];
  const float* pos = (const float*)d_in[1];
  const float* Wq  = (const float*)d_in[2];
  const float* bq  = (const float*)d_in[3];
  const float* Wk  = (const float*)d_in[4];
  const float* bk  = (const float*)d_in[5];
  const float* Wv  = (const float*)d_in[6];
  const float* bv  = (const float*)d_in[7];
  const float* Wo  = (const float*)d_in[8];
  const float* bo  = (const float*)d_in[9];

  float* outp  = (float*)d_out;          // [B,S,D] f32
  float* attnp = outp + BSD;             // [B,S,S] f32 (final attn)

  // workspace layout (~176 MB of the ~768 MB ws)
  _Float16* wqkv = (_Float16*)d_ws;              // [3072][1024] f16 (6 MB)
  _Float16* woh  = wqkv + 3 * DD;                // [1024][1024] f16 (2 MB)
  float*    bcat = (float*)(woh + DD);           // [3072] f32
  float*    pwtab = bcat + 3072;                 // [2048] f32
  _Float16* qh  = (_Float16*)(pwtab + 2048);     // [B*S][D] f16 (33.5 MB)
  _Float16* kh  = qh + BSD;                      // [B*S][D]
  _Float16* vt  = kh + BSD;                      // [B][D][S]
  _Float16* sbf = vt + BSD;                      // [B][S][S] f16 scores (67 MB)
  _Float16* abf = sbf + (long)B * SS;            // [B][S][S] f16 attn (67 MB)
  _Float16* hbf = qh;                            // PV out reuses qh (dead after scores)

  // xp f16 lives in the (not-yet-written) attn region of d_out
  _Float16* xph = (_Float16*)attnp;

  dim3 blk(256);
  prep_w_kernel<<<dim3(16, 16), blk, 0, stream>>>(Wq, Wk, Wv, Wo, wqkv, woh);
  prep_misc_kernel<<<dim3(20), blk, 0, stream>>>(bq, bk, bv, bcat, pwtab);
  prep_x_kernel<<<dim3((int)(BSD / 1024)), blk, 0, stream>>>(x, pos, xph);

  // fused QKV projection: [16384,1024] @ [3072,1024]^T
  dim3 gQKV(3 * D / 128, (B * S) / 128, 1);   // (24,128,1)
  gemm_kernel<EPI_QKV><<<gQKV, blk, 0, stream>>>(
      xph, wqkv, bcat, nullptr, nullptr, qh, kh, vt, B * S, 3 * D, D, 0, 0, 0);

  // scores (f16, pw-scaled): per-batch [2048,1024] @ [2048,1024]^T
  dim3 gScore(S / 128, S / 128, B);           // (16,16,8)
  gemm_kernel<EPI_SF16><<<gScore, blk, 0, stream>>>(
      qh, kh, nullptr, pwtab, nullptr, sbf, nullptr, nullptr, S, S, D, SD, SD, SS);

  softmax_kernel<<<dim3(B * S), blk, 0, stream>>>(sbf, attnp, abf);

  // PV: per-batch [2048,2048] @ [1024,2048]^T
  dim3 gPV(D / 128, S / 128, B);              // (8,16,8)
  gemm_kernel<EPI_PVO><<<gPV, blk, 0, stream>>>(
      abf, vt, nullptr, nullptr, nullptr, hbf, nullptr, nullptr, S, D, S, SS, SD, SD);

  // out-proj: [16384,1024] @ [1024,1024]^T + bo -> f32
  dim3 gOut(D / 128, (B * S) / 128, 1);       // (8,128,1)
  gemm_kernel<EPI_F32B><<<gOut, blk, 0, stream>>>(
      hbf, woh, bo, nullptr, outp, nullptr, nullptr, nullptr, B * S, D, D, 0, 0, 0);
}

// Round 5
// 472.486 us; speedup vs baseline: 2.0083x; 1.0392x over previous
//
#include <hip/hip_runtime.h>
#include <hip/hip_bf16.h>
#include <cstdint>

typedef _Float16 f16x8 __attribute__((ext_vector_type(8)));
typedef _Float16 f16x4 __attribute__((ext_vector_type(4)));
typedef float    f32x4 __attribute__((ext_vector_type(4)));

static constexpr int B = 8, S = 2048, D = 1024;
static constexpr long BSD = (long)B * S * D;   // 16,777,216
static constexpr long SD  = (long)S * D;       // 2,097,152
static constexpr long SS  = (long)S * S;       // 4,194,304
static constexpr long DD  = (long)D * D;       // 1,048,576

__device__ __forceinline__ void gload16(const void* g, void* l) {
  __builtin_amdgcn_global_load_lds(
      (const __attribute__((address_space(1))) void*)g,
      (__attribute__((address_space(3))) void*)l, 16, 0, 0);
}

// ---------------- prep: xp = x + pos -> f16 ----------------
__global__ __launch_bounds__(256) void prep_x_kernel(
    const float* __restrict__ x, const float* __restrict__ pos,
    _Float16* __restrict__ xh) {
  long i = ((long)blockIdx.x * 256 + threadIdx.x) * 4;
  float4 xv = *(const float4*)(x + i);
  long p = i & (SD - 1);
  float4 pv = *(const float4*)(pos + p);
  f16x4 h;
  h.x = (_Float16)(xv.x + pv.x);
  h.y = (_Float16)(xv.y + pv.y);
  h.z = (_Float16)(xv.z + pv.z);
  h.w = (_Float16)(xv.w + pv.w);
  *(f16x4*)(xh + i) = h;
}

// ---------------- prep: weights -> transposed f16, LDS-tiled ----------------
__global__ __launch_bounds__(256) void prep_w_kernel(
    const float* __restrict__ Wq, const float* __restrict__ Wk,
    const float* __restrict__ Wv, const float* __restrict__ Wo,
    _Float16* __restrict__ wqkv, _Float16* __restrict__ woh) {
  __shared__ _Float16 t[64][65];
  const int c0 = blockIdx.x * 64;
  const int r0 = blockIdx.y * 64;
  const int tid = threadIdx.x;
  const int lc = tid & 63;
  const int lr4 = tid >> 6;
  const float* srcs[4] = {Wq, Wk, Wv, Wo};
  #pragma unroll
  for (int m = 0; m < 4; ++m) {
    const float* src = srcs[m];
    _Float16* dst = (m < 3) ? (wqkv + (long)m * DD) : woh;
    #pragma unroll
    for (int ii = 0; ii < 16; ++ii) {
      int row = ii * 4 + lr4;
      t[lc][row] = (_Float16)src[(long)(r0 + row) * D + c0 + lc];
    }
    __syncthreads();
    #pragma unroll
    for (int ii = 0; ii < 16; ++ii) {
      int orow = ii * 4 + lr4;
      dst[(long)(c0 + orow) * D + r0 + lc] = t[orow][lc];
    }
    __syncthreads();
  }
}

// ---------------- prep: bias concat + pw table ----------------
__global__ __launch_bounds__(256) void prep_misc_kernel(
    const float* __restrict__ bq, const float* __restrict__ bk,
    const float* __restrict__ bv,
    float* __restrict__ bcat, float* __restrict__ pwtab) {
  int i = blockIdx.x * 256 + threadIdx.x;
  if (i < 3072) {
    float v = (i < 1024) ? bq[i] : (i < 2048) ? bk[i - 1024] : bv[i - 2048];
    bcat[i] = v;
  }
  int d = i - 3072;
  if (d >= 0 && d < 2048) {
    float dist = (float)d * (1.0f / 2048.0f);
    pwtab[d] = (1.0f + 1.5f * expf(-2.0f * dist)) * (1.0f / 2.5f) * (1.0f / 32.0f);
  }
}

// ============ 256x256 8-phase MFMA GEMM: C[M,N] = A[M,K] * Bt[N,K]^T ============
// LDS: buf p (p<2) at p*65536; A halves at +0/+16384, B halves at +32768/+49152.
// Each 16KB half = 8 rowgrp x 2 colgrp subtiles of 1024B ([16 rows][32 cols] f16),
// st_16x32 swizzle: byte ^= ((byte>>9)&1)<<5, applied as pre-swizzled global
// source on stage + XOR'd ds_read address (both-sides involution, rule #21).

enum { EPI_QKV = 0, EPI_SF16 = 1, EPI_PVO = 2, EPI_F32B = 3 };

__device__ __forceinline__ void stage_half(
    char* smem, const _Float16* mb, int matK, int h, int kt, int sthb,
    int rowc, int colc, int dst0, int dst1) {
  const _Float16* s0 = mb + (long)(rowc + h * 128) * matK + kt * 64 + colc;
  const _Float16* s1 = mb + (long)(rowc + 64 + h * 128) * matK + kt * 64 + colc;
  gload16(s0, smem + sthb + dst0);
  gload16(s1, smem + sthb + dst1);
}

template<int QM, int QN, bool VMQ>
__device__ __forceinline__ void phase_op(
    char* smem, int curbase, int wm4, int wn2, int rtail,
    f32x4 (&acc)[2][2][4][2],
    bool doStg, const _Float16* mb, int matK, int h, int kt, int sthb,
    int rowc, int colc, int dst0, int dst1)
{
  f16x8 af[4][2], bf[2][2];
#pragma unroll
  for (int mr = 0; mr < 4; ++mr)
#pragma unroll
    for (int kk = 0; kk < 2; ++kk)
      af[mr][kk] = *(const f16x8*)(smem + curbase + QM * 16384 +
                                   (wm4 + mr) * 2048 + kk * 1024 + rtail);
#pragma unroll
  for (int nr = 0; nr < 2; ++nr)
#pragma unroll
    for (int kk = 0; kk < 2; ++kk)
      bf[nr][kk] = *(const f16x8*)(smem + curbase + 32768 + QN * 16384 +
                                   (wn2 + nr) * 2048 + kk * 1024 + rtail);
  if (doStg)
    stage_half(smem, mb, matK, h, kt, sthb, rowc, colc, dst0, dst1);
  __builtin_amdgcn_s_barrier();
  asm volatile("s_waitcnt lgkmcnt(0)" ::: "memory");
  __builtin_amdgcn_sched_barrier(0);
  __builtin_amdgcn_s_setprio(1);
#pragma unroll
  for (int kk = 0; kk < 2; ++kk)
#pragma unroll
    for (int mr = 0; mr < 4; ++mr)
#pragma unroll
      for (int nr = 0; nr < 2; ++nr)
        acc[QM][QN][mr][nr] = __builtin_amdgcn_mfma_f32_16x16x32_f16(
            af[mr][kk], bf[nr][kk], acc[QM][QN][mr][nr], 0, 0, 0);
  __builtin_amdgcn_s_setprio(0);
  if (VMQ) {
    asm volatile("s_waitcnt vmcnt(4)" ::: "memory");
    __builtin_amdgcn_sched_barrier(0);
  }
  __builtin_amdgcn_s_barrier();
  __builtin_amdgcn_sched_barrier(0);
}

template<int EPI>
__global__ __launch_bounds__(512, 2) void gemm256_kernel(
    const _Float16* __restrict__ A, const _Float16* __restrict__ Bt,
    const float* __restrict__ bias, const float* __restrict__ pwtab,
    float* __restrict__ outF,
    _Float16* __restrict__ o0, _Float16* __restrict__ o1, _Float16* __restrict__ o2,
    int M, int N, int K, long sA, long sB, long sC)
{
  __shared__ __align__(16) char smem[131072];
  const int tid = threadIdx.x;
  const int z = blockIdx.z;
  const int rb = blockIdx.y * 256;
  const int cb = blockIdx.x * 256;
  const _Float16* Ag = A + (long)z * sA + (long)rb * K;
  const _Float16* Bg = Bt + (long)z * sB + (long)cb * K;

  const int lane = tid & 63;
  const int wid = tid >> 6;
  const int wm4 = (wid >> 2) * 4;     // A rowgrp base for this wave
  const int wn2 = (wid & 3) * 2;      // B rowgrp base for this wave
  const int lrin = lane & 15;
  const int lhi = lane >> 4;
  const int rtail = (lrin * 64 + lhi * 16) ^ (((lane >> 3) & 1) << 5);

  // stage-side per-thread constants (dest chunk c = tid and tid+512)
  const int rin = lane >> 2;                               // 0..15
  const int cinp = (lane & 3) ^ (((lane >> 5) & 1) << 1);  // source pre-swizzle
  const int rowc = (wid >> 1) * 16 + rin;
  const int colc = (wid & 1) * 32 + cinp * 8;
  const int dst0 = tid * 16;
  const int dst1 = 8192 + tid * 16;

  const int NT = K >> 6;
  f32x4 acc[2][2][4][2] = {};

  // prologue: tile0 all 4 halves -> buf0; A0,B1 of tile1 -> buf1 (issued last)
  stage_half(smem, Ag, K, 0, 0, 0,             rowc, colc, dst0, dst1);
  stage_half(smem, Bg, K, 0, 0, 32768,         rowc, colc, dst0, dst1);
  stage_half(smem, Ag, K, 1, 0, 16384,         rowc, colc, dst0, dst1);
  stage_half(smem, Bg, K, 1, 0, 49152,         rowc, colc, dst0, dst1);
  stage_half(smem, Ag, K, 0, 1, 65536,         rowc, colc, dst0, dst1);
  stage_half(smem, Bg, K, 1, 1, 65536 + 49152, rowc, colc, dst0, dst1);
  asm volatile("s_waitcnt vmcnt(4)" ::: "memory");
  __builtin_amdgcn_sched_barrier(0);
  __builtin_amdgcn_s_barrier();
  __builtin_amdgcn_sched_barrier(0);

  for (int t = 0; t < NT; ++t) {
    const int curbase = (t & 1) << 16;
    const int nxtbase = curbase ^ 65536;
    const bool s1ok = (t + 1) < NT;
    const bool s2ok = (t + 2) < NT;
    // c1: quad(A0,B0); stage A1(t+1) -> nxt buf
    phase_op<0, 0, false>(smem, curbase, wm4, wn2, rtail, acc,
        s1ok, Ag, K, 1, t + 1, nxtbase + 16384, rowc, colc, dst0, dst1);
    // c2: quad(A0,B1); stage B0(t+1) -> nxt buf
    phase_op<0, 1, false>(smem, curbase, wm4, wn2, rtail, acc,
        s1ok, Bg, K, 0, t + 1, nxtbase + 32768, rowc, colc, dst0, dst1);
    // c3: quad(A1,B1); stage A0(t+2) -> cur buf (A0 slot free after c2)
    phase_op<1, 1, false>(smem, curbase, wm4, wn2, rtail, acc,
        s2ok, Ag, K, 0, t + 2, curbase + 0, rowc, colc, dst0, dst1);
    // c4: quad(A1,B0); stage B1(t+2) -> cur buf (B1 slot free after c3); vmcnt gate
    phase_op<1, 0, true>(smem, curbase, wm4, wn2, rtail, acc,
        s2ok, Bg, K, 1, t + 2, curbase + 49152, rowc, colc, dst0, dst1);
  }

  // epilogue: C/D layout col = lane&15, row = (lane>>4)*4 + r  [m89-verified]
  const int wrow = (wid >> 2) * 64;
  const int wcol = (wid & 3) * 32;
#pragma unroll
  for (int qm = 0; qm < 2; ++qm)
#pragma unroll
  for (int qn = 0; qn < 2; ++qn)
#pragma unroll
  for (int nr = 0; nr < 2; ++nr) {
    const int col = cb + qn * 128 + wcol + nr * 16 + lrin;
    float bv = 0.0f;
    if (EPI == EPI_QKV || EPI == EPI_F32B) bv = bias[col];
#pragma unroll
    for (int mr = 0; mr < 4; ++mr) {
      const int rowb = rb + qm * 128 + wrow + mr * 16 + lhi * 4;
      const f32x4 v4 = acc[qm][qn][mr][nr];
#pragma unroll
      for (int r = 0; r < 4; ++r) {
        const int row = rowb + r;
        const float v = v4[r];
        if (EPI == EPI_QKV) {
          const int matid = cb >> 10;
          _Float16* dst = (matid == 0) ? o0 : (matid == 1) ? o1 : o2;
          const int cl = col & 1023;
          const float vb = v + bv;
          if (matid < 2) {
            dst[(long)row * 1024 + cl] = (_Float16)vb;
          } else {
            const int bb = row >> 11;
            const int trow = row & (S - 1);
            dst[(long)bb * SD + (long)cl * S + trow] = (_Float16)vb;
          }
        } else if (EPI == EPI_SF16) {
          int dd = row - col; if (dd < 0) dd = -dd;
          o0[(long)z * sC + (long)row * N + col] = (_Float16)(v * pwtab[dd]);
        } else if (EPI == EPI_PVO) {
          o0[(long)z * sC + (long)row * N + col] = (_Float16)v;
        } else {  // EPI_F32B
          outF[(long)row * N + col] = v + bv;
        }
      }
    }
  }
}

// ---------------- row softmax over 2048: f16 in -> f32 attn + f16 copy ----------------
__global__ __launch_bounds__(256) void softmax_kernel(
    const _Float16* __restrict__ sbf, float* __restrict__ attn,
    _Float16* __restrict__ abf) {
  const long base = (long)blockIdx.x * S + threadIdx.x * 8;
  const int tid = threadIdx.x;
  const f16x8 sv = *(const f16x8*)(sbf + base);
  float v[8];
  #pragma unroll
  for (int t = 0; t < 8; ++t) v[t] = (float)sv[t];
  float m = fmaxf(fmaxf(fmaxf(v[0], v[1]), fmaxf(v[2], v[3])),
                  fmaxf(fmaxf(v[4], v[5]), fmaxf(v[6], v[7])));
  #pragma unroll
  for (int sh = 1; sh < 64; sh <<= 1) m = fmaxf(m, __shfl_xor(m, sh));
  __shared__ float red[8];
  const int w = tid >> 6;
  if ((tid & 63) == 0) red[w] = m;
  __syncthreads();
  m = fmaxf(fmaxf(red[0], red[1]), fmaxf(red[2], red[3]));
  float e[8];
  #pragma unroll
  for (int t = 0; t < 8; ++t) e[t] = expf(v[t] - m);
  float s8 = ((e[0] + e[1]) + (e[2] + e[3])) + ((e[4] + e[5]) + (e[6] + e[7]));
  #pragma unroll
  for (int sh = 1; sh < 64; sh <<= 1) s8 += __shfl_xor(s8, sh);
  if ((tid & 63) == 0) red[4 + w] = s8;
  __syncthreads();
  const float inv = 1.0f / ((red[4] + red[5]) + (red[6] + red[7]));
  float4 o0 = make_float4(e[0] * inv, e[1] * inv, e[2] * inv, e[3] * inv);
  float4 o1 = make_float4(e[4] * inv, e[5] * inv, e[6] * inv, e[7] * inv);
  *(float4*)(attn + base) = o0;
  *(float4*)(attn + base + 4) = o1;
  f16x8 hb;
  hb[0] = (_Float16)o0.x; hb[1] = (_Float16)o0.y;
  hb[2] = (_Float16)o0.z; hb[3] = (_Float16)o0.w;
  hb[4] = (_Float16)o1.x; hb[5] = (_Float16)o1.y;
  hb[6] = (_Float16)o1.z; hb[7] = (_Float16)o1.w;
  *(f16x8*)(abf + base) = hb;
}

extern "C" void kernel_launch(void* const* d_in, const int* in_sizes, int n_in,
                              void* d_out, int out_size, void* d_ws, size_t ws_size,
                              hipStream_t stream) {
  const float* x   = (const float*)d_in[0];
  const float* pos = (const float*)d_in[1];
  const float* Wq  = (const float*)d_in[2];
  const float* bq  = (const float*)d_in[3];
  const float* Wk  = (const float*)d_in[4];
  const float* bk  = (const float*)d_in[5];
  const float* Wv  = (const float*)d_in[6];
  const float* bv  = (const float*)d_in[7];
  const float* Wo  = (const float*)d_in[8];
  const float* bo  = (const float*)d_in[9];

  float* outp  = (float*)d_out;          // [B,S,D] f32
  float* attnp = outp + BSD;             // [B,S,S] f32 (final attn)

  // workspace layout (~243 MB of ws)
  _Float16* wqkv = (_Float16*)d_ws;              // [3072][1024] f16
  _Float16* woh  = wqkv + 3 * DD;                // [1024][1024] f16
  float*    bcat = (float*)(woh + DD);           // [3072] f32
  float*    pwtab = bcat + 3072;                 // [2048] f32
  _Float16* qh  = (_Float16*)(pwtab + 2048);     // [B*S][D] f16
  _Float16* kh  = qh + BSD;                      // [B*S][D]
  _Float16* vt  = kh + BSD;                      // [B][D][S]
  _Float16* sbf = vt + BSD;                      // [B][S][S] f16 scores
  _Float16* abf = sbf + (long)B * SS;            // [B][S][S] f16 attn
  _Float16* hbf = qh;                            // PV out reuses qh

  _Float16* xph = (_Float16*)attnp;              // xp f16 in attn region of d_out

  dim3 blk(256);
  prep_w_kernel<<<dim3(16, 16), blk, 0, stream>>>(Wq, Wk, Wv, Wo, wqkv, woh);
  prep_misc_kernel<<<dim3(20), blk, 0, stream>>>(bq, bk, bv, bcat, pwtab);
  prep_x_kernel<<<dim3((int)(BSD / 1024)), blk, 0, stream>>>(x, pos, xph);

  dim3 blk5(512);
  // fused QKV projection: [16384,1024] @ [3072,1024]^T
  gemm256_kernel<EPI_QKV><<<dim3(12, 64, 1), blk5, 0, stream>>>(
      xph, wqkv, bcat, nullptr, nullptr, qh, kh, vt, B * S, 3 * D, D, 0, 0, 0);

  // scores (f16, pw-scaled): per-batch [2048,1024] @ [2048,1024]^T
  gemm256_kernel<EPI_SF16><<<dim3(8, 8, B), blk5, 0, stream>>>(
      qh, kh, nullptr, pwtab, nullptr, sbf, nullptr, nullptr, S, S, D, SD, SD, SS);

  softmax_kernel<<<dim3(B * S), blk, 0, stream>>>(sbf, attnp, abf);

  // PV: per-batch [2048,2048] @ [1024,2048]^T
  gemm256_kernel<EPI_PVO><<<dim3(4, 8, B), blk5, 0, stream>>>(
      abf, vt, nullptr, nullptr, nullptr, hbf, nullptr, nullptr, S, D, S, SS, SD, SD);

  // out-proj: [16384,1024] @ [1024,1024]^T + bo -> f32
  gemm256_kernel<EPI_F32B><<<dim3(4, 64, 1), blk5, 0, stream>>>(
      hbf, woh, bo, nullptr, outp, nullptr, nullptr, nullptr, B * S, D, D, 0, 0, 0);
}

// Round 7
// 438.886 us; speedup vs baseline: 2.1621x; 1.0766x over previous
//
#include <hip/hip_runtime.h>
#include <hip/hip_bf16.h>
#include <cstdint>

typedef _Float16 f16x8 __attribute__((ext_vector_type(8)));
typedef _Float16 f16x4 __attribute__((ext_vector_type(4)));
typedef float    f32x4 __attribute__((ext_vector_type(4)));

static constexpr int B = 8, S = 2048, D = 1024;
static constexpr long BSD = (long)B * S * D;   // 16,777,216
static constexpr long SD  = (long)S * D;       // 2,097,152
static constexpr long SS  = (long)S * S;       // 4,194,304
static constexpr long DD  = (long)D * D;       // 1,048,576

__device__ __forceinline__ void gload16(const void* g, void* l) {
  __builtin_amdgcn_global_load_lds(
      (const __attribute__((address_space(1))) void*)g,
      (__attribute__((address_space(3))) void*)l, 16, 0, 0);
}

// ---------------- prep: xp = x + pos -> f16 ----------------
__global__ __launch_bounds__(256) void prep_x_kernel(
    const float* __restrict__ x, const float* __restrict__ pos,
    _Float16* __restrict__ xh) {
  long i = ((long)blockIdx.x * 256 + threadIdx.x) * 4;
  float4 xv = *(const float4*)(x + i);
  long p = i & (SD - 1);
  float4 pv = *(const float4*)(pos + p);
  f16x4 h;
  h.x = (_Float16)(xv.x + pv.x);
  h.y = (_Float16)(xv.y + pv.y);
  h.z = (_Float16)(xv.z + pv.z);
  h.w = (_Float16)(xv.w + pv.w);
  *(f16x4*)(xh + i) = h;
}

// ---------------- prep: weights -> transposed f16, LDS-tiled ----------------
__global__ __launch_bounds__(256) void prep_w_kernel(
    const float* __restrict__ Wq, const float* __restrict__ Wk,
    const float* __restrict__ Wv, const float* __restrict__ Wo,
    _Float16* __restrict__ wqkv, _Float16* __restrict__ woh) {
  __shared__ _Float16 t[64][65];
  const int c0 = blockIdx.x * 64;
  const int r0 = blockIdx.y * 64;
  const int tid = threadIdx.x;
  const int lc = tid & 63;
  const int lr4 = tid >> 6;
  const float* srcs[4] = {Wq, Wk, Wv, Wo};
  #pragma unroll
  for (int m = 0; m < 4; ++m) {
    const float* src = srcs[m];
    _Float16* dst = (m < 3) ? (wqkv + (long)m * DD) : woh;
    #pragma unroll
    for (int ii = 0; ii < 16; ++ii) {
      int row = ii * 4 + lr4;
      t[lc][row] = (_Float16)src[(long)(r0 + row) * D + c0 + lc];
    }
    __syncthreads();
    #pragma unroll
    for (int ii = 0; ii < 16; ++ii) {
      int orow = ii * 4 + lr4;
      dst[(long)(c0 + orow) * D + r0 + lc] = t[orow][lc];
    }
    __syncthreads();
  }
}

// ---------------- prep: bias concat + pw table ----------------
__global__ __launch_bounds__(256) void prep_misc_kernel(
    const float* __restrict__ bq, const float* __restrict__ bk,
    const float* __restrict__ bv,
    float* __restrict__ bcat, float* __restrict__ pwtab) {
  int i = blockIdx.x * 256 + threadIdx.x;
  if (i < 3072) {
    float v = (i < 1024) ? bq[i] : (i < 2048) ? bk[i - 1024] : bv[i - 2048];
    bcat[i] = v;
  }
  int d = i - 3072;
  if (d >= 0 && d < 2048) {
    float dist = (float)d * (1.0f / 2048.0f);
    pwtab[d] = (1.0f + 1.5f * expf(-2.0f * dist)) * (1.0f / 2.5f) * (1.0f / 32.0f);
  }
}

// ============ 256x256 8-phase MFMA GEMM: C[M,N] = A[M,K] * Bt[N,K]^T ============
// LDS: buf p (p<2) at p*65536; A halves at +0/+16384, B halves at +32768/+49152.
// st_16x32 swizzle via pre-swizzled global source + XOR'd ds_read (rule #21).
// Quadrant order (A0B0)->(A0B1)->(A1B1)->(A1B0); 28 ds_read_b128/wave/K-tile.
// vmcnt ledger: steady state vmcnt(4) at c4 retires through c2's stage (A1,B0
// of t+1); tiles t+1/t+2 read only epoch-retired slots. TAIL: when s2ok is
// false the c3/c4 stages are skipped, so vmcnt(4) would leave c1/c2's stages
// (inputs of tile NT-1!) un-retired -> use vmcnt(0) there (R6 race fix).

enum { EPI_QKV = 0, EPI_SF16 = 1, EPI_PVO = 2, EPI_F32B = 3 };

__device__ __forceinline__ void stage_half(
    char* smem, const _Float16* mb, int matK, int h, int kt, int sthb,
    int rowc, int colc, int dst0, int dst1) {
  const _Float16* s0 = mb + (long)(rowc + h * 128) * matK + kt * 64 + colc;
  const _Float16* s1 = mb + (long)(rowc + 64 + h * 128) * matK + kt * 64 + colc;
  gload16(s0, smem + sthb + dst0);
  gload16(s1, smem + sthb + dst1);
}

__device__ __forceinline__ void rdA(const char* p, f16x8 (&af)[4][2]) {
#pragma unroll
  for (int mr = 0; mr < 4; ++mr)
#pragma unroll
    for (int kk = 0; kk < 2; ++kk)
      af[mr][kk] = *(const f16x8*)(p + mr * 2048 + kk * 1024);
}

__device__ __forceinline__ void rdB(const char* p, f16x8 (&bf)[2][2]) {
#pragma unroll
  for (int nr = 0; nr < 2; ++nr)
#pragma unroll
    for (int kk = 0; kk < 2; ++kk)
      bf[nr][kk] = *(const f16x8*)(p + nr * 2048 + kk * 1024);
}

__device__ __forceinline__ void mfma16(const f16x8 (&af)[4][2],
                                       const f16x8 (&bf)[2][2],
                                       f32x4 (&a4)[4][2]) {
#pragma unroll
  for (int kk = 0; kk < 2; ++kk)
#pragma unroll
    for (int mr = 0; mr < 4; ++mr)
#pragma unroll
      for (int nr = 0; nr < 2; ++nr)
        a4[mr][nr] = __builtin_amdgcn_mfma_f32_16x16x32_f16(
            af[mr][kk], bf[nr][kk], a4[mr][nr], 0, 0, 0);
}

template<int EPI>
__global__ __launch_bounds__(512, 2) void gemm256_kernel(
    const _Float16* __restrict__ A, const _Float16* __restrict__ Bt,
    const float* __restrict__ bias, const float* __restrict__ pwtab,
    float* __restrict__ outF,
    _Float16* __restrict__ o0, _Float16* __restrict__ o1, _Float16* __restrict__ o2,
    int M, int N, int K, long sA, long sB, long sC)
{
  __shared__ __align__(16) char smem[131072];
  const int tid = threadIdx.x;
  const int z = blockIdx.z;

  // T1 XCD swizzle (z==1 grids only; gridDim.y==64, nwg%8==0, bijective):
  // XCD k owns 8 row-slabs; panel-outer/slab-inner keeps the xph slab-set
  // (4 MB) L2-resident across weight panels.
  int bx = blockIdx.x, by = blockIdx.y;
  if (gridDim.z == 1) {
    const int bid = by * gridDim.x + bx;
    const int idx = bid >> 3;
    by = ((bid & 7) << 3) + (idx & 7);
    bx = idx >> 3;
  }
  const int rb = by * 256;
  const int cb = bx * 256;
  const _Float16* Ag = A + (long)z * sA + (long)rb * K;
  const _Float16* Bg = Bt + (long)z * sB + (long)cb * K;

  const int lane = tid & 63;
  const int wid = tid >> 6;
  const int lrin = lane & 15;
  const int lhi = lane >> 4;
  const int rtail = (lrin * 64 + lhi * 16) ^ (((lane >> 3) & 1) << 5);
  const int aoff = ((wid >> 2) * 4) * 2048 + rtail;   // A rowgrp base
  const int boff = ((wid & 3) * 2) * 2048 + rtail;    // B rowgrp base

  // stage-side per-thread constants
  const int rin = lane >> 2;
  const int cinp = (lane & 3) ^ (((lane >> 5) & 1) << 1);  // source pre-swizzle
  const int rowc = (wid >> 1) * 16 + rin;
  const int colc = (wid & 1) * 32 + cinp * 8;
  const int dst0 = tid * 16;
  const int dst1 = 8192 + tid * 16;

  const int NT = K >> 6;
  f32x4 acc00[4][2] = {}, acc01[4][2] = {}, acc11[4][2] = {}, acc10[4][2] = {};

  // prologue: tile0 all 4 halves -> buf0; A0,B1 of tile1 -> buf1
  stage_half(smem, Ag, K, 0, 0, 0,             rowc, colc, dst0, dst1);
  stage_half(smem, Bg, K, 0, 0, 32768,         rowc, colc, dst0, dst1);
  stage_half(smem, Ag, K, 1, 0, 16384,         rowc, colc, dst0, dst1);
  stage_half(smem, Bg, K, 1, 0, 49152,         rowc, colc, dst0, dst1);
  stage_half(smem, Ag, K, 0, 1, 65536,         rowc, colc, dst0, dst1);
  stage_half(smem, Bg, K, 1, 1, 65536 + 49152, rowc, colc, dst0, dst1);
  asm volatile("s_waitcnt vmcnt(4)" ::: "memory");
  __builtin_amdgcn_sched_barrier(0);
  __builtin_amdgcn_s_barrier();
  __builtin_amdgcn_sched_barrier(0);

  for (int t = 0; t < NT; ++t) {
    const int curbase = (t & 1) << 16;
    const int nxtbase = curbase ^ 65536;
    const bool s1ok = (t + 1) < NT;
    const bool s2ok = (t + 2) < NT;
    f16x8 af[4][2], bfA[2][2], bfB[2][2];

    // ---- c1: read A0,B0; MFMA quad(0,0); stage A1(t+1) -> nxt
    rdA((const char*)smem + curbase + aoff, af);
    rdB((const char*)smem + curbase + 32768 + boff, bfA);
    if (s1ok) stage_half(smem, Ag, K, 1, t + 1, nxtbase + 16384, rowc, colc, dst0, dst1);
    __builtin_amdgcn_s_barrier();
    asm volatile("s_waitcnt lgkmcnt(0)" ::: "memory");
    __builtin_amdgcn_sched_barrier(0);
    __builtin_amdgcn_s_setprio(1);
    mfma16(af, bfA, acc00);
    __builtin_amdgcn_s_setprio(0);
    __builtin_amdgcn_s_barrier();
    __builtin_amdgcn_sched_barrier(0);

    // ---- c2: read B1 (A0 reused); MFMA quad(0,1); stage B0(t+1) -> nxt
    rdB((const char*)smem + curbase + 49152 + boff, bfB);
    if (s1ok) stage_half(smem, Bg, K, 0, t + 1, nxtbase + 32768, rowc, colc, dst0, dst1);
    __builtin_amdgcn_s_barrier();
    asm volatile("s_waitcnt lgkmcnt(0)" ::: "memory");
    __builtin_amdgcn_sched_barrier(0);
    __builtin_amdgcn_s_setprio(1);
    mfma16(af, bfB, acc01);
    __builtin_amdgcn_s_setprio(0);
    __builtin_amdgcn_s_barrier();
    __builtin_amdgcn_sched_barrier(0);

    // ---- c3: read A1 (B1 reused); MFMA quad(1,1); stage A0(t+2) -> cur
    rdA((const char*)smem + curbase + 16384 + aoff, af);
    if (s2ok) stage_half(smem, Ag, K, 0, t + 2, curbase + 0, rowc, colc, dst0, dst1);
    __builtin_amdgcn_s_barrier();
    asm volatile("s_waitcnt lgkmcnt(0)" ::: "memory");
    __builtin_amdgcn_sched_barrier(0);
    __builtin_amdgcn_s_setprio(1);
    mfma16(af, bfB, acc11);
    __builtin_amdgcn_s_setprio(0);
    __builtin_amdgcn_s_barrier();
    __builtin_amdgcn_sched_barrier(0);

    // ---- c4: re-read B0 (A1 reused); MFMA quad(1,0); stage B1(t+2) -> cur; vm gate
    rdB((const char*)smem + curbase + 32768 + boff, bfA);
    if (s2ok) stage_half(smem, Bg, K, 1, t + 2, curbase + 49152, rowc, colc, dst0, dst1);
    __builtin_amdgcn_s_barrier();
    asm volatile("s_waitcnt lgkmcnt(0)" ::: "memory");
    __builtin_amdgcn_sched_barrier(0);
    __builtin_amdgcn_s_setprio(1);
    mfma16(af, bfA, acc10);
    __builtin_amdgcn_s_setprio(0);
    if (s2ok) {
      asm volatile("s_waitcnt vmcnt(4)" ::: "memory");
    } else {
      // tail: c3/c4 stages skipped -> vmcnt(4) would leave c1/c2's stages
      // (tile NT-1's A1,B0!) outstanding. Drain fully. (R6 race fix)
      asm volatile("s_waitcnt vmcnt(0)" ::: "memory");
    }
    __builtin_amdgcn_sched_barrier(0);
    __builtin_amdgcn_s_barrier();
    __builtin_amdgcn_sched_barrier(0);
  }

  // epilogue: C/D layout col = lane&15, row = (lane>>4)*4 + r  [m89-verified]
  const int wrow = (wid >> 2) * 64;
  const int wcol = (wid & 3) * 32;
  auto epi = [&](const f32x4 (&a4)[4][2], int qm, int qn) {
#pragma unroll
    for (int nr = 0; nr < 2; ++nr) {
      const int col = cb + qn * 128 + wcol + nr * 16 + lrin;
      float bv = 0.0f;
      if (EPI == EPI_QKV || EPI == EPI_F32B) bv = bias[col];
#pragma unroll
      for (int mr = 0; mr < 4; ++mr) {
        const int rowb = rb + qm * 128 + wrow + mr * 16 + lhi * 4;
        const f32x4 v4 = a4[mr][nr];
#pragma unroll
        for (int r = 0; r < 4; ++r) {
          const int row = rowb + r;
          const float v = v4[r];
          if (EPI == EPI_QKV) {
            const int matid = cb >> 10;
            _Float16* dst = (matid == 0) ? o0 : (matid == 1) ? o1 : o2;
            const int cl = col & 1023;
            const float vb = v + bv;
            if (matid < 2) {
              dst[(long)row * 1024 + cl] = (_Float16)vb;
            } else {
              const int bb = row >> 11;
              const int trow = row & (S - 1);
              dst[(long)bb * SD + (long)cl * S + trow] = (_Float16)vb;
            }
          } else if (EPI == EPI_SF16) {
            int dd = row - col; if (dd < 0) dd = -dd;
            o0[(long)z * sC + (long)row * N + col] = (_Float16)(v * pwtab[dd]);
          } else if (EPI == EPI_PVO) {
            o0[(long)z * sC + (long)row * N + col] = (_Float16)v;
          } else {  // EPI_F32B
            outF[(long)row * N + col] = v + bv;
          }
        }
      }
    }
  };
  epi(acc00, 0, 0);
  epi(acc01, 0, 1);
  epi(acc11, 1, 1);
  epi(acc10, 1, 0);
}

// ---------------- row softmax over 2048: f16 in -> f32 attn + f16 copy ----------------
__global__ __launch_bounds__(256) void softmax_kernel(
    const _Float16* __restrict__ sbf, float* __restrict__ attn,
    _Float16* __restrict__ abf) {
  const long base = (long)blockIdx.x * S + threadIdx.x * 8;
  const int tid = threadIdx.x;
  const f16x8 sv = *(const f16x8*)(sbf + base);
  float v[8];
  #pragma unroll
  for (int t = 0; t < 8; ++t) v[t] = (float)sv[t];
  float m = fmaxf(fmaxf(fmaxf(v[0], v[1]), fmaxf(v[2], v[3])),
                  fmaxf(fmaxf(v[4], v[5]), fmaxf(v[6], v[7])));
  #pragma unroll
  for (int sh = 1; sh < 64; sh <<= 1) m = fmaxf(m, __shfl_xor(m, sh));
  __shared__ float red[8];
  const int w = tid >> 6;
  if ((tid & 63) == 0) red[w] = m;
  __syncthreads();
  m = fmaxf(fmaxf(red[0], red[1]), fmaxf(red[2], red[3]));
  float e[8];
  #pragma unroll
  for (int t = 0; t < 8; ++t) e[t] = expf(v[t] - m);
  float s8 = ((e[0] + e[1]) + (e[2] + e[3])) + ((e[4] + e[5]) + (e[6] + e[7]));
  #pragma unroll
  for (int sh = 1; sh < 64; sh <<= 1) s8 += __shfl_xor(s8, sh);
  if ((tid & 63) == 0) red[4 + w] = s8;
  __syncthreads();
  const float inv = 1.0f / ((red[4] + red[5]) + (red[6] + red[7]));
  float4 o0 = make_float4(e[0] * inv, e[1] * inv, e[2] * inv, e[3] * inv);
  float4 o1 = make_float4(e[4] * inv, e[5] * inv, e[6] * inv, e[7] * inv);
  *(float4*)(attn + base) = o0;
  *(float4*)(attn + base + 4) = o1;
  f16x8 hb;
  hb[0] = (_Float16)o0.x; hb[1] = (_Float16)o0.y;
  hb[2] = (_Float16)o0.z; hb[3] = (_Float16)o0.w;
  hb[4] = (_Float16)o1.x; hb[5] = (_Float16)o1.y;
  hb[6] = (_Float16)o1.z; hb[7] = (_Float16)o1.w;
  *(f16x8*)(abf + base) = hb;
}

extern "C" void kernel_launch(void* const* d_in, const int* in_sizes, int n_in,
                              void* d_out, int out_size, void* d_ws, size_t ws_size,
                              hipStream_t stream) {
  const float* x   = (const float*)d_in[0];
  const float* pos = (const float*)d_in[1];
  const float* Wq  = (const float*)d_in[2];
  const float* bq  = (const float*)d_in[3];
  const float* Wk  = (const float*)d_in[4];
  const float* bk  = (const float*)d_in[5];
  const float* Wv  = (const float*)d_in[6];
  const float* bv  = (const float*)d_in[7];
  const float* Wo  = (const float*)d_in[8];
  const float* bo  = (const float*)d_in[9];

  float* outp  = (float*)d_out;          // [B,S,D] f32
  float* attnp = outp + BSD;             // [B,S,S] f32 (final attn)

  // workspace layout (~243 MB of ws)
  _Float16* wqkv = (_Float16*)d_ws;              // [3072][1024] f16
  _Float16* woh  = wqkv + 3 * DD;                // [1024][1024] f16
  float*    bcat = (float*)(woh + DD);           // [3072] f32
  float*    pwtab = bcat + 3072;                 // [2048] f32
  _Float16* qh  = (_Float16*)(pwtab + 2048);     // [B*S][D] f16
  _Float16* kh  = qh + BSD;                      // [B*S][D]
  _Float16* vt  = kh + BSD;                      // [B][D][S]
  _Float16* sbf = vt + BSD;                      // [B][S][S] f16 scores
  _Float16* abf = sbf + (long)B * SS;            // [B][S][S] f16 attn
  _Float16* hbf = qh;                            // PV out reuses qh

  _Float16* xph = (_Float16*)attnp;              // xp f16 in attn region of d_out

  dim3 blk(256);
  prep_w_kernel<<<dim3(16, 16), blk, 0, stream>>>(Wq, Wk, Wv, Wo, wqkv, woh);
  prep_misc_kernel<<<dim3(20), blk, 0, stream>>>(bq, bk, bv, bcat, pwtab);
  prep_x_kernel<<<dim3((int)(BSD / 1024)), blk, 0, stream>>>(x, pos, xph);

  dim3 blk5(512);
  // fused QKV projection: [16384,1024] @ [3072,1024]^T
  gemm256_kernel<EPI_QKV><<<dim3(12, 64, 1), blk5, 0, stream>>>(
      xph, wqkv, bcat, nullptr, nullptr, qh, kh, vt, B * S, 3 * D, D, 0, 0, 0);

  // scores (f16, pw-scaled): per-batch [2048,1024] @ [2048,1024]^T
  gemm256_kernel<EPI_SF16><<<dim3(8, 8, B), blk5, 0, stream>>>(
      qh, kh, nullptr, pwtab, nullptr, sbf, nullptr, nullptr, S, S, D, SD, SD, SS);

  softmax_kernel<<<dim3(B * S), blk, 0, stream>>>(sbf, attnp, abf);

  // PV: per-batch [2048,2048] @ [1024,2048]^T
  gemm256_kernel<EPI_PVO><<<dim3(4, 8, B), blk5, 0, stream>>>(
      abf, vt, nullptr, nullptr, nullptr, hbf, nullptr, nullptr, S, D, S, SS, SD, SD);

  // out-proj: [16384,1024] @ [1024,1024]^T + bo -> f32
  gemm256_kernel<EPI_F32B><<<dim3(4, 64, 1), blk5, 0, stream>>>(
      hbf, woh, bo, nullptr, outp, nullptr, nullptr, nullptr, B * S, D, D, 0, 0, 0);
}

// Round 8
// 436.268 us; speedup vs baseline: 2.1750x; 1.0060x over previous
//
#include <hip/hip_runtime.h>
#include <hip/hip_bf16.h>
#include <cstdint>

typedef _Float16 f16x8 __attribute__((ext_vector_type(8)));
typedef _Float16 f16x4 __attribute__((ext_vector_type(4)));
typedef float    f32x4 __attribute__((ext_vector_type(4)));

static constexpr int B = 8, S = 2048, D = 1024;
static constexpr long BSD = (long)B * S * D;   // 16,777,216
static constexpr long SD  = (long)S * D;       // 2,097,152
static constexpr long SS  = (long)S * S;       // 4,194,304
static constexpr long DD  = (long)D * D;       // 1,048,576

__device__ __forceinline__ void gload16(const void* g, void* l) {
  __builtin_amdgcn_global_load_lds(
      (const __attribute__((address_space(1))) void*)g,
      (__attribute__((address_space(3))) void*)l, 16, 0, 0);
}

// compile-time memory fence: no instruction, blocks memory-op reordering
#define CFENCE() asm volatile("" ::: "memory")

// ---------------- prep: xp = x + pos -> f16 ----------------
__global__ __launch_bounds__(256) void prep_x_kernel(
    const float* __restrict__ x, const float* __restrict__ pos,
    _Float16* __restrict__ xh) {
  long i = ((long)blockIdx.x * 256 + threadIdx.x) * 4;
  float4 xv = *(const float4*)(x + i);
  long p = i & (SD - 1);
  float4 pv = *(const float4*)(pos + p);
  f16x4 h;
  h.x = (_Float16)(xv.x + pv.x);
  h.y = (_Float16)(xv.y + pv.y);
  h.z = (_Float16)(xv.z + pv.z);
  h.w = (_Float16)(xv.w + pv.w);
  *(f16x4*)(xh + i) = h;
}

// ---------------- prep: weights -> transposed f16, LDS-tiled ----------------
__global__ __launch_bounds__(256) void prep_w_kernel(
    const float* __restrict__ Wq, const float* __restrict__ Wk,
    const float* __restrict__ Wv, const float* __restrict__ Wo,
    _Float16* __restrict__ wqkv, _Float16* __restrict__ woh) {
  __shared__ _Float16 t[64][65];
  const int c0 = blockIdx.x * 64;
  const int r0 = blockIdx.y * 64;
  const int tid = threadIdx.x;
  const int lc = tid & 63;
  const int lr4 = tid >> 6;
  const float* srcs[4] = {Wq, Wk, Wv, Wo};
  #pragma unroll
  for (int m = 0; m < 4; ++m) {
    const float* src = srcs[m];
    _Float16* dst = (m < 3) ? (wqkv + (long)m * DD) : woh;
    #pragma unroll
    for (int ii = 0; ii < 16; ++ii) {
      int row = ii * 4 + lr4;
      t[lc][row] = (_Float16)src[(long)(r0 + row) * D + c0 + lc];
    }
    __syncthreads();
    #pragma unroll
    for (int ii = 0; ii < 16; ++ii) {
      int orow = ii * 4 + lr4;
      dst[(long)(c0 + orow) * D + r0 + lc] = t[orow][lc];
    }
    __syncthreads();
  }
}

// ---------------- prep: bias concat + pw table ----------------
__global__ __launch_bounds__(256) void prep_misc_kernel(
    const float* __restrict__ bq, const float* __restrict__ bk,
    const float* __restrict__ bv,
    float* __restrict__ bcat, float* __restrict__ pwtab) {
  int i = blockIdx.x * 256 + threadIdx.x;
  if (i < 3072) {
    float v = (i < 1024) ? bq[i] : (i < 2048) ? bk[i - 1024] : bv[i - 2048];
    bcat[i] = v;
  }
  int d = i - 3072;
  if (d >= 0 && d < 2048) {
    float dist = (float)d * (1.0f / 2048.0f);
    pwtab[d] = (1.0f + 1.5f * expf(-2.0f * dist)) * (1.0f / 2.5f) * (1.0f / 32.0f);
  }
}

// ============ 256x256 8-phase MFMA GEMM: C[M,N] = A[M,K] * Bt[N,K]^T ============
// LDS: buf p (p<2) at p*65536; A halves at +0/+16384, B halves at +32768/+49152.
// st_16x32 swizzle via pre-swizzled global source + XOR'd ds_read (rule #21).
// Phases use C++ ds_reads (compiler-managed precise lgkmcnt) + raw s_barrier +
// CFENCE() compile-time fences; NO sched_barrier / lgkmcnt(0) pins (m141).
// vmcnt ledger unchanged from R7 (counted vmcnt(4); tail drains vmcnt(0)).

enum { EPI_QKV = 0, EPI_SF16 = 1, EPI_PVO = 2, EPI_F32B = 3 };

__device__ __forceinline__ void stage_half(
    char* smem, const _Float16* mb, int off, int k64K, int sthb,
    int dst0, int dst1) {
  gload16(mb + off, smem + sthb + dst0);
  gload16(mb + off + k64K, smem + sthb + dst1);
}

__device__ __forceinline__ void rdA(const char* p, f16x8 (&af)[4][2]) {
#pragma unroll
  for (int mr = 0; mr < 4; ++mr)
#pragma unroll
    for (int kk = 0; kk < 2; ++kk)
      af[mr][kk] = *(const f16x8*)(p + mr * 2048 + kk * 1024);
}

__device__ __forceinline__ void rdB(const char* p, f16x8 (&bf)[2][2]) {
#pragma unroll
  for (int nr = 0; nr < 2; ++nr)
#pragma unroll
    for (int kk = 0; kk < 2; ++kk)
      bf[nr][kk] = *(const f16x8*)(p + nr * 2048 + kk * 1024);
}

__device__ __forceinline__ void mfma16(const f16x8 (&af)[4][2],
                                       const f16x8 (&bf)[2][2],
                                       f32x4 (&a4)[4][2]) {
#pragma unroll
  for (int kk = 0; kk < 2; ++kk)
#pragma unroll
    for (int mr = 0; mr < 4; ++mr)
#pragma unroll
      for (int nr = 0; nr < 2; ++nr)
        a4[mr][nr] = __builtin_amdgcn_mfma_f32_16x16x32_f16(
            af[mr][kk], bf[nr][kk], a4[mr][nr], 0, 0, 0);
}

template<int EPI>
__global__ __launch_bounds__(512, 2) void gemm256_kernel(
    const _Float16* __restrict__ A, const _Float16* __restrict__ Bt,
    const float* __restrict__ bias, const float* __restrict__ pwtab,
    float* __restrict__ outF,
    _Float16* __restrict__ o0, _Float16* __restrict__ o1, _Float16* __restrict__ o2,
    int M, int N, int K, long sA, long sB, long sC)
{
  __shared__ __align__(16) char smem[131072];
  const int tid = threadIdx.x;
  const int z = blockIdx.z;

  // T1 XCD swizzle (z==1 grids only; bijective for nwg%8==0):
  int bx = blockIdx.x, by = blockIdx.y;
  if (gridDim.z == 1) {
    const int bid = by * gridDim.x + bx;
    const int idx = bid >> 3;
    by = ((bid & 7) << 3) + (idx & 7);
    bx = idx >> 3;
  }
  const int rb = by * 256;
  const int cb = bx * 256;
  const _Float16* Ag = A + (long)z * sA + (long)rb * K;
  const _Float16* Bg = Bt + (long)z * sB + (long)cb * K;

  const int lane = tid & 63;
  const int wid = tid >> 6;
  const int lrin = lane & 15;
  const int lhi = lane >> 4;
  const int rtail = (lrin * 64 + lhi * 16) ^ (((lane >> 3) & 1) << 5);
  const int aoff = ((wid >> 2) * 4) * 2048 + rtail;   // A rowgrp base
  const int boff = ((wid & 3) * 2) * 2048 + rtail;    // B rowgrp base

  // stage-side per-thread constants (int offsets; 64-bit add only at use)
  const int rin = lane >> 2;
  const int cinp = (lane & 3) ^ (((lane >> 5) & 1) << 1);  // source pre-swizzle
  const int rowc = (wid >> 1) * 16 + rin;
  const int colc = (wid & 1) * 32 + cinp * 8;
  const int stBase = rowc * K + colc;   // elem offset of this thread's chunk
  const int k64K = 64 * K;              // +64 rows
  const int h128K = 128 * K;            // +128 rows (half 1)
  const int dst0 = tid * 16;
  const int dst1 = 8192 + tid * 16;

  const int NT = K >> 6;
  f32x4 acc00[4][2] = {}, acc01[4][2] = {}, acc11[4][2] = {}, acc10[4][2] = {};

  // prologue: tile0 all 4 halves -> buf0; A0,B1 of tile1 -> buf1
  stage_half(smem, Ag, stBase,              k64K, 0,             dst0, dst1);
  stage_half(smem, Bg, stBase,              k64K, 32768,         dst0, dst1);
  stage_half(smem, Ag, stBase + h128K,      k64K, 16384,         dst0, dst1);
  stage_half(smem, Bg, stBase + h128K,      k64K, 49152,         dst0, dst1);
  stage_half(smem, Ag, stBase + 64,         k64K, 65536,         dst0, dst1);
  stage_half(smem, Bg, stBase + h128K + 64, k64K, 65536 + 49152, dst0, dst1);
  asm volatile("s_waitcnt vmcnt(4)" ::: "memory");
  __builtin_amdgcn_s_barrier();
  CFENCE();

  for (int t = 0; t < NT; ++t) {
    const int curbase = (t & 1) << 16;
    const int nxtbase = curbase ^ 65536;
    const bool s1ok = (t + 1) < NT;
    const bool s2ok = (t + 2) < NT;
    const int st1 = stBase + (t + 1) * 64;   // K-offset of tile t+1
    const int st2 = stBase + (t + 2) * 64;   // K-offset of tile t+2
    f16x8 af[4][2], bfA[2][2], bfB[2][2];

    // ---- c1: read A0,B0; MFMA quad(0,0); stage A1(t+1) -> nxt
    rdA((const char*)smem + curbase + aoff, af);
    rdB((const char*)smem + curbase + 32768 + boff, bfA);
    if (s1ok) stage_half(smem, Ag, st1 + h128K, k64K, nxtbase + 16384, dst0, dst1);
    CFENCE();
    __builtin_amdgcn_s_barrier();
    CFENCE();
    __builtin_amdgcn_s_setprio(1);
    mfma16(af, bfA, acc00);
    __builtin_amdgcn_s_setprio(0);
    CFENCE();
    __builtin_amdgcn_s_barrier();
    CFENCE();

    // ---- c2: read B1 (A0 reused); MFMA quad(0,1); stage B0(t+1) -> nxt
    rdB((const char*)smem + curbase + 49152 + boff, bfB);
    if (s1ok) stage_half(smem, Bg, st1, k64K, nxtbase + 32768, dst0, dst1);
    CFENCE();
    __builtin_amdgcn_s_barrier();
    CFENCE();
    __builtin_amdgcn_s_setprio(1);
    mfma16(af, bfB, acc01);
    __builtin_amdgcn_s_setprio(0);
    CFENCE();
    __builtin_amdgcn_s_barrier();
    CFENCE();

    // ---- c3: read A1 (B1 reused); MFMA quad(1,1); stage A0(t+2) -> cur
    rdA((const char*)smem + curbase + 16384 + aoff, af);
    if (s2ok) stage_half(smem, Ag, st2, k64K, curbase + 0, dst0, dst1);
    CFENCE();
    __builtin_amdgcn_s_barrier();
    CFENCE();
    __builtin_amdgcn_s_setprio(1);
    mfma16(af, bfB, acc11);
    __builtin_amdgcn_s_setprio(0);
    CFENCE();
    __builtin_amdgcn_s_barrier();
    CFENCE();

    // ---- c4: re-read B0 (A1 reused); MFMA quad(1,0); stage B1(t+2) -> cur; vm gate
    rdB((const char*)smem + curbase + 32768 + boff, bfA);
    if (s2ok) stage_half(smem, Bg, st2 + h128K, k64K, curbase + 49152, dst0, dst1);
    CFENCE();
    __builtin_amdgcn_s_barrier();
    CFENCE();
    __builtin_amdgcn_s_setprio(1);
    mfma16(af, bfA, acc10);
    __builtin_amdgcn_s_setprio(0);
    if (s2ok) {
      asm volatile("s_waitcnt vmcnt(4)" ::: "memory");
    } else {
      // tail: c3/c4 stages skipped -> drain fully (R6 race fix)
      asm volatile("s_waitcnt vmcnt(0)" ::: "memory");
    }
    __builtin_amdgcn_s_barrier();
    CFENCE();
  }

  // epilogue: C/D layout col = lane&15, row = (lane>>4)*4 + r  [m89-verified]
  const int wrow = (wid >> 2) * 64;
  const int wcol = (wid & 3) * 32;
  auto epi = [&](const f32x4 (&a4)[4][2], int qm, int qn) {
#pragma unroll
    for (int nr = 0; nr < 2; ++nr) {
      const int col = cb + qn * 128 + wcol + nr * 16 + lrin;
      float bv = 0.0f;
      if (EPI == EPI_QKV || EPI == EPI_F32B) bv = bias[col];
#pragma unroll
      for (int mr = 0; mr < 4; ++mr) {
        const int rowb = rb + qm * 128 + wrow + mr * 16 + lhi * 4;
        const f32x4 v4 = a4[mr][nr];
#pragma unroll
        for (int r = 0; r < 4; ++r) {
          const int row = rowb + r;
          const float v = v4[r];
          if (EPI == EPI_QKV) {
            const int matid = cb >> 10;
            _Float16* dst = (matid == 0) ? o0 : (matid == 1) ? o1 : o2;
            const int cl = col & 1023;
            const float vb = v + bv;
            if (matid < 2) {
              dst[(long)row * 1024 + cl] = (_Float16)vb;
            } else {
              const int bb = row >> 11;
              const int trow = row & (S - 1);
              dst[(long)bb * SD + (long)cl * S + trow] = (_Float16)vb;
            }
          } else if (EPI == EPI_SF16) {
            int dd = row - col; if (dd < 0) dd = -dd;
            o0[(long)z * sC + (long)row * N + col] = (_Float16)(v * pwtab[dd]);
          } else if (EPI == EPI_PVO) {
            o0[(long)z * sC + (long)row * N + col] = (_Float16)v;
          } else {  // EPI_F32B
            outF[(long)row * N + col] = v + bv;
          }
        }
      }
    }
  };
  epi(acc00, 0, 0);
  epi(acc01, 0, 1);
  epi(acc11, 1, 1);
  epi(acc10, 1, 0);
}

// ---------------- row softmax over 2048: f16 in -> f32 attn + f16 copy ----------------
__global__ __launch_bounds__(256) void softmax_kernel(
    const _Float16* __restrict__ sbf, float* __restrict__ attn,
    _Float16* __restrict__ abf) {
  const long base = (long)blockIdx.x * S + threadIdx.x * 8;
  const int tid = threadIdx.x;
  const f16x8 sv = *(const f16x8*)(sbf + base);
  float v[8];
  #pragma unroll
  for (int t = 0; t < 8; ++t) v[t] = (float)sv[t];
  float m = fmaxf(fmaxf(fmaxf(v[0], v[1]), fmaxf(v[2], v[3])),
                  fmaxf(fmaxf(v[4], v[5]), fmaxf(v[6], v[7])));
  #pragma unroll
  for (int sh = 1; sh < 64; sh <<= 1) m = fmaxf(m, __shfl_xor(m, sh));
  __shared__ float red[8];
  const int w = tid >> 6;
  if ((tid & 63) == 0) red[w] = m;
  __syncthreads();
  m = fmaxf(fmaxf(red[0], red[1]), fmaxf(red[2], red[3]));
  float e[8];
  #pragma unroll
  for (int t = 0; t < 8; ++t) e[t] = expf(v[t] - m);
  float s8 = ((e[0] + e[1]) + (e[2] + e[3])) + ((e[4] + e[5]) + (e[6] + e[7]));
  #pragma unroll
  for (int sh = 1; sh < 64; sh <<= 1) s8 += __shfl_xor(s8, sh);
  if ((tid & 63) == 0) red[4 + w] = s8;
  __syncthreads();
  const float inv = 1.0f / ((red[4] + red[5]) + (red[6] + red[7]));
  float4 o0 = make_float4(e[0] * inv, e[1] * inv, e[2] * inv, e[3] * inv);
  float4 o1 = make_float4(e[4] * inv, e[5] * inv, e[6] * inv, e[7] * inv);
  *(float4*)(attn + base) = o0;
  *(float4*)(attn + base + 4) = o1;
  f16x8 hb;
  hb[0] = (_Float16)o0.x; hb[1] = (_Float16)o0.y;
  hb[2] = (_Float16)o0.z; hb[3] = (_Float16)o0.w;
  hb[4] = (_Float16)o1.x; hb[5] = (_Float16)o1.y;
  hb[6] = (_Float16)o1.z; hb[7] = (_Float16)o1.w;
  *(f16x8*)(abf + base) = hb;
}

extern "C" void kernel_launch(void* const* d_in, const int* in_sizes, int n_in,
                              void* d_out, int out_size, void* d_ws, size_t ws_size,
                              hipStream_t stream) {
  const float* x   = (const float*)d_in[0];
  const float* pos = (const float*)d_in[1];
  const float* Wq  = (const float*)d_in[2];
  const float* bq  = (const float*)d_in[3];
  const float* Wk  = (const float*)d_in[4];
  const float* bk  = (const float*)d_in[5];
  const float* Wv  = (const float*)d_in[6];
  const float* bv  = (const float*)d_in[7];
  const float* Wo  = (const float*)d_in[8];
  const float* bo  = (const float*)d_in[9];

  float* outp  = (float*)d_out;          // [B,S,D] f32
  float* attnp = outp + BSD;             // [B,S,S] f32 (final attn)

  // workspace layout (~243 MB of ws)
  _Float16* wqkv = (_Float16*)d_ws;              // [3072][1024] f16
  _Float16* woh  = wqkv + 3 * DD;                // [1024][1024] f16
  float*    bcat = (float*)(woh + DD);           // [3072] f32
  float*    pwtab = bcat + 3072;                 // [2048] f32
  _Float16* qh  = (_Float16*)(pwtab + 2048);     // [B*S][D] f16
  _Float16* kh  = qh + BSD;                      // [B*S][D]
  _Float16* vt  = kh + BSD;                      // [B][D][S]
  _Float16* sbf = vt + BSD;                      // [B][S][S] f16 scores
  _Float16* abf = sbf + (long)B * SS;            // [B][S][S] f16 attn
  _Float16* hbf = qh;                            // PV out reuses qh

  _Float16* xph = (_Float16*)attnp;              // xp f16 in attn region of d_out

  dim3 blk(256);
  prep_w_kernel<<<dim3(16, 16), blk, 0, stream>>>(Wq, Wk, Wv, Wo, wqkv, woh);
  prep_misc_kernel<<<dim3(20), blk, 0, stream>>>(bq, bk, bv, bcat, pwtab);
  prep_x_kernel<<<dim3((int)(BSD / 1024)), blk, 0, stream>>>(x, pos, xph);

  dim3 blk5(512);
  // fused QKV projection: [16384,1024] @ [3072,1024]^T
  gemm256_kernel<EPI_QKV><<<dim3(12, 64, 1), blk5, 0, stream>>>(
      xph, wqkv, bcat, nullptr, nullptr, qh, kh, vt, B * S, 3 * D, D, 0, 0, 0);

  // scores (f16, pw-scaled): per-batch [2048,1024] @ [2048,1024]^T
  gemm256_kernel<EPI_SF16><<<dim3(8, 8, B), blk5, 0, stream>>>(
      qh, kh, nullptr, pwtab, nullptr, sbf, nullptr, nullptr, S, S, D, SD, SD, SS);

  softmax_kernel<<<dim3(B * S), blk, 0, stream>>>(sbf, attnp, abf);

  // PV: per-batch [2048,2048] @ [1024,2048]^T
  gemm256_kernel<EPI_PVO><<<dim3(4, 8, B), blk5, 0, stream>>>(
      abf, vt, nullptr, nullptr, nullptr, hbf, nullptr, nullptr, S, D, S, SS, SD, SD);

  // out-proj: [16384,1024] @ [1024,1024]^T + bo -> f32
  gemm256_kernel<EPI_F32B><<<dim3(4, 64, 1), blk5, 0, stream>>>(
      hbf, woh, bo, nullptr, outp, nullptr, nullptr, nullptr, B * S, D, D, 0, 0, 0);
}

// Round 9
// 378.707 us; speedup vs baseline: 2.5056x; 1.1520x over previous
//
#include <hip/hip_runtime.h>
#include <hip/hip_bf16.h>
#include <cstdint>

typedef _Float16 f16x8 __attribute__((ext_vector_type(8)));
typedef _Float16 f16x4 __attribute__((ext_vector_type(4)));
typedef float    f32x4 __attribute__((ext_vector_type(4)));

static constexpr int B = 8, S = 2048, D = 1024;
static constexpr long BSD = (long)B * S * D;   // 16,777,216
static constexpr long SD  = (long)S * D;       // 2,097,152
static constexpr long SS  = (long)S * S;       // 4,194,304
static constexpr long DD  = (long)D * D;       // 1,048,576

__device__ __forceinline__ void gload16(const void* g, void* l) {
  __builtin_amdgcn_global_load_lds(
      (const __attribute__((address_space(1))) void*)g,
      (__attribute__((address_space(3))) void*)l, 16, 0, 0);
}

// compile-time memory fence: no instruction, blocks memory-op reordering
#define CFENCE() asm volatile("" ::: "memory")

// ---------------- prep: xp = x + pos -> f16 ----------------
__global__ __launch_bounds__(256) void prep_x_kernel(
    const float* __restrict__ x, const float* __restrict__ pos,
    _Float16* __restrict__ xh) {
  long i = ((long)blockIdx.x * 256 + threadIdx.x) * 4;
  float4 xv = *(const float4*)(x + i);
  long p = i & (SD - 1);
  float4 pv = *(const float4*)(pos + p);
  f16x4 h;
  h.x = (_Float16)(xv.x + pv.x);
  h.y = (_Float16)(xv.y + pv.y);
  h.z = (_Float16)(xv.z + pv.z);
  h.w = (_Float16)(xv.w + pv.w);
  *(f16x4*)(xh + i) = h;
}

// ---------------- prep: weights -> transposed f16, LDS-tiled ----------------
__global__ __launch_bounds__(256) void prep_w_kernel(
    const float* __restrict__ Wq, const float* __restrict__ Wk,
    const float* __restrict__ Wv, const float* __restrict__ Wo,
    _Float16* __restrict__ wqkv, _Float16* __restrict__ woh) {
  __shared__ _Float16 t[64][65];
  const int c0 = blockIdx.x * 64;
  const int r0 = blockIdx.y * 64;
  const int tid = threadIdx.x;
  const int lc = tid & 63;
  const int lr4 = tid >> 6;
  const float* srcs[4] = {Wq, Wk, Wv, Wo};
  #pragma unroll
  for (int m = 0; m < 4; ++m) {
    const float* src = srcs[m];
    _Float16* dst = (m < 3) ? (wqkv + (long)m * DD) : woh;
    #pragma unroll
    for (int ii = 0; ii < 16; ++ii) {
      int row = ii * 4 + lr4;
      t[lc][row] = (_Float16)src[(long)(r0 + row) * D + c0 + lc];
    }
    __syncthreads();
    #pragma unroll
    for (int ii = 0; ii < 16; ++ii) {
      int orow = ii * 4 + lr4;
      dst[(long)(c0 + orow) * D + r0 + lc] = t[orow][lc];
    }
    __syncthreads();
  }
}

// ---------------- prep: bias concat + pw table ----------------
__global__ __launch_bounds__(256) void prep_misc_kernel(
    const float* __restrict__ bq, const float* __restrict__ bk,
    const float* __restrict__ bv,
    float* __restrict__ bcat, float* __restrict__ pwtab) {
  int i = blockIdx.x * 256 + threadIdx.x;
  if (i < 3072) {
    float v = (i < 1024) ? bq[i] : (i < 2048) ? bk[i - 1024] : bv[i - 2048];
    bcat[i] = v;
  }
  int d = i - 3072;
  if (d >= 0 && d < 2048) {
    float dist = (float)d * (1.0f / 2048.0f);
    pwtab[d] = (1.0f + 1.5f * expf(-2.0f * dist)) * (1.0f / 2.5f) * (1.0f / 32.0f);
  }
}

// ============ 256x256 8-phase MFMA GEMM: C[M,N] = A[M,K] * Bt[N,K]^T ============
// LDS: buf p (p<2) at p*65536; A halves at +0/+16384, B halves at +32768/+49152.
// st_16x32 swizzle via pre-swizzled global source + XOR'd ds_read (rule #21).
// SINGLE barrier per phase (R9): {reads; stage; [c4: vm gate]; BAR; MFMA}.
// Ledger: every slot's last reader completes its ds_reads (compiler lgkm wait
// before its MFMA) >=1 barrier before the overwriting stage issues; verified
// per slot incl. cross-iteration (A1/B0 of cur overwritten by next iter's
// c1/c2 only after BAR(c1/c2 of t+1), by which the reader passed its MFMA).
// vmcnt: counted vmcnt(4) at c4; tail (s2ok false) drains vmcnt(0) [R6 fix].

enum { EPI_QKV = 0, EPI_SF16 = 1, EPI_PVO = 2, EPI_F32B = 3 };

__device__ __forceinline__ void stage_half(
    char* smem, const _Float16* mb, int off, int k64K, int sthb,
    int dst0, int dst1) {
  gload16(mb + off, smem + sthb + dst0);
  gload16(mb + off + k64K, smem + sthb + dst1);
}

__device__ __forceinline__ void rdA(const char* p, f16x8 (&af)[4][2]) {
#pragma unroll
  for (int mr = 0; mr < 4; ++mr)
#pragma unroll
    for (int kk = 0; kk < 2; ++kk)
      af[mr][kk] = *(const f16x8*)(p + mr * 2048 + kk * 1024);
}

__device__ __forceinline__ void rdB(const char* p, f16x8 (&bf)[2][2]) {
#pragma unroll
  for (int nr = 0; nr < 2; ++nr)
#pragma unroll
    for (int kk = 0; kk < 2; ++kk)
      bf[nr][kk] = *(const f16x8*)(p + nr * 2048 + kk * 1024);
}

__device__ __forceinline__ void mfma16(const f16x8 (&af)[4][2],
                                       const f16x8 (&bf)[2][2],
                                       f32x4 (&a4)[4][2]) {
#pragma unroll
  for (int kk = 0; kk < 2; ++kk)
#pragma unroll
    for (int mr = 0; mr < 4; ++mr)
#pragma unroll
      for (int nr = 0; nr < 2; ++nr)
        a4[mr][nr] = __builtin_amdgcn_mfma_f32_16x16x32_f16(
            af[mr][kk], bf[nr][kk], a4[mr][nr], 0, 0, 0);
}

template<int EPI>
__global__ __launch_bounds__(512, 2) void gemm256_kernel(
    const _Float16* __restrict__ A, const _Float16* __restrict__ Bt,
    const float* __restrict__ bias, const float* __restrict__ pwtab,
    float* __restrict__ outF,
    _Float16* __restrict__ o0, _Float16* __restrict__ o1, _Float16* __restrict__ o2,
    int M, int N, int K, long sA, long sB, long sC)
{
  __shared__ __align__(16) char smem[131072];
  const int tid = threadIdx.x;
  const int z = blockIdx.z;

  // T1 XCD swizzle (z==1 grids only; bijective for nwg%8==0):
  int bx = blockIdx.x, by = blockIdx.y;
  if (gridDim.z == 1) {
    const int bid = by * gridDim.x + bx;
    const int idx = bid >> 3;
    by = ((bid & 7) << 3) + (idx & 7);
    bx = idx >> 3;
  }
  const int rb = by * 256;
  const int cb = bx * 256;
  const _Float16* Ag = A + (long)z * sA + (long)rb * K;
  const _Float16* Bg = Bt + (long)z * sB + (long)cb * K;

  const int lane = tid & 63;
  const int wid = tid >> 6;
  const int lrin = lane & 15;
  const int lhi = lane >> 4;
  const int rtail = (lrin * 64 + lhi * 16) ^ (((lane >> 3) & 1) << 5);
  const int aoff = ((wid >> 2) * 4) * 2048 + rtail;   // A rowgrp base
  const int boff = ((wid & 3) * 2) * 2048 + rtail;    // B rowgrp base

  // stage-side per-thread constants (int offsets; 64-bit add only at use)
  const int rin = lane >> 2;
  const int cinp = (lane & 3) ^ (((lane >> 5) & 1) << 1);  // source pre-swizzle
  const int rowc = (wid >> 1) * 16 + rin;
  const int colc = (wid & 1) * 32 + cinp * 8;
  const int stBase = rowc * K + colc;   // elem offset of this thread's chunk
  const int k64K = 64 * K;              // +64 rows
  const int h128K = 128 * K;            // +128 rows (half 1)
  const int dst0 = tid * 16;
  const int dst1 = 8192 + tid * 16;

  const int NT = K >> 6;
  f32x4 acc00[4][2] = {}, acc01[4][2] = {}, acc11[4][2] = {}, acc10[4][2] = {};

  // prologue: tile0 all 4 halves -> buf0; A0,B1 of tile1 -> buf1
  stage_half(smem, Ag, stBase,              k64K, 0,             dst0, dst1);
  stage_half(smem, Bg, stBase,              k64K, 32768,         dst0, dst1);
  stage_half(smem, Ag, stBase + h128K,      k64K, 16384,         dst0, dst1);
  stage_half(smem, Bg, stBase + h128K,      k64K, 49152,         dst0, dst1);
  stage_half(smem, Ag, stBase + 64,         k64K, 65536,         dst0, dst1);
  stage_half(smem, Bg, stBase + h128K + 64, k64K, 65536 + 49152, dst0, dst1);
  asm volatile("s_waitcnt vmcnt(4)" ::: "memory");
  __builtin_amdgcn_s_barrier();
  CFENCE();

  for (int t = 0; t < NT; ++t) {
    const int curbase = (t & 1) << 16;
    const int nxtbase = curbase ^ 65536;
    const bool s1ok = (t + 1) < NT;
    const bool s2ok = (t + 2) < NT;
    const int st1 = stBase + (t + 1) * 64;   // K-offset of tile t+1
    const int st2 = stBase + (t + 2) * 64;   // K-offset of tile t+2
    f16x8 af[4][2], bfA[2][2], bfB[2][2];

    // ---- c1: read A0,B0; stage A1(t+1)->nxt; BAR; MFMA quad(0,0)
    rdA((const char*)smem + curbase + aoff, af);
    rdB((const char*)smem + curbase + 32768 + boff, bfA);
    if (s1ok) stage_half(smem, Ag, st1 + h128K, k64K, nxtbase + 16384, dst0, dst1);
    CFENCE();
    __builtin_amdgcn_s_barrier();
    CFENCE();
    __builtin_amdgcn_s_setprio(1);
    mfma16(af, bfA, acc00);
    __builtin_amdgcn_s_setprio(0);

    // ---- c2: read B1 (A0 reused); stage B0(t+1)->nxt; BAR; MFMA quad(0,1)
    rdB((const char*)smem + curbase + 49152 + boff, bfB);
    if (s1ok) stage_half(smem, Bg, st1, k64K, nxtbase + 32768, dst0, dst1);
    CFENCE();
    __builtin_amdgcn_s_barrier();
    CFENCE();
    __builtin_amdgcn_s_setprio(1);
    mfma16(af, bfB, acc01);
    __builtin_amdgcn_s_setprio(0);

    // ---- c3: read A1 (B1 reused); stage A0(t+2)->cur; BAR; MFMA quad(1,1)
    rdA((const char*)smem + curbase + 16384 + aoff, af);
    if (s2ok) stage_half(smem, Ag, st2, k64K, curbase + 0, dst0, dst1);
    CFENCE();
    __builtin_amdgcn_s_barrier();
    CFENCE();
    __builtin_amdgcn_s_setprio(1);
    mfma16(af, bfB, acc11);
    __builtin_amdgcn_s_setprio(0);

    // ---- c4: re-read B0 (A1 reused); stage B1(t+2)->cur; vm gate; BAR; MFMA quad(1,0)
    rdB((const char*)smem + curbase + 32768 + boff, bfA);
    if (s2ok) stage_half(smem, Bg, st2 + h128K, k64K, curbase + 49152, dst0, dst1);
    if (s2ok) {
      asm volatile("s_waitcnt vmcnt(4)" ::: "memory");
    } else {
      asm volatile("s_waitcnt vmcnt(0)" ::: "memory");  // tail drain (R6 fix)
    }
    CFENCE();
    __builtin_amdgcn_s_barrier();
    CFENCE();
    __builtin_amdgcn_s_setprio(1);
    mfma16(af, bfA, acc10);
    __builtin_amdgcn_s_setprio(0);
  }

  // epilogue: C/D layout col = lane&15, row = (lane>>4)*4 + r  [m89-verified]
  const int wrow = (wid >> 2) * 64;
  const int wcol = (wid & 3) * 32;
  const int matid = (EPI == EPI_QKV) ? (cb >> 10) : 0;

  if (EPI == EPI_QKV && matid == 2) {
    // ---- V: LDS-transpose epilogue (coalesced [d][t] stores) ----
    // smem reused as 256(d) x 256(t) f16 = 128 KB, XOR swizzle bit4 ^= (d&7)<<4.
    __syncthreads();   // all waves' K-loop LDS reads complete
    auto vfrag = [&](const f32x4 (&a4)[4][2], int qm, int qn) {
#pragma unroll
      for (int nr = 0; nr < 2; ++nr) {
        const int dl = qn * 128 + wcol + nr * 16 + lrin;   // 0..255
        const float bv = bias[cb + dl];
        const int xr = (dl & 7) << 4;
#pragma unroll
        for (int mr = 0; mr < 4; ++mr) {
          const int tl = qm * 128 + wrow + mr * 16 + lhi * 4;  // 0..252 step 4
          const f32x4 v4 = a4[mr][nr];
          f16x4 p;
          p[0] = (_Float16)(v4[0] + bv);
          p[1] = (_Float16)(v4[1] + bv);
          p[2] = (_Float16)(v4[2] + bv);
          p[3] = (_Float16)(v4[3] + bv);
          *(f16x4*)(smem + dl * 512 + ((tl * 2) ^ xr)) = p;
        }
      }
    };
    vfrag(acc00, 0, 0);
    vfrag(acc01, 0, 1);
    vfrag(acc11, 1, 1);
    vfrag(acc10, 1, 0);
    __syncthreads();
    const int t0 = rb & (S - 1);
    const int bbk = rb >> 11;
    const int lr5 = tid & 31;       // 32 threads per d-row
    const int dr0 = tid >> 5;       // 0..15
#pragma unroll
    for (int pass = 0; pass < 16; ++pass) {
      const int dl = pass * 16 + dr0;
      const f16x8 vv = *(const f16x8*)(smem + dl * 512 + ((lr5 * 16) ^ ((dl & 7) << 4)));
      *(f16x8*)(o2 + (long)bbk * SD + (long)(cb - 2048 + dl) * S + t0 + lr5 * 8) = vv;
    }
  } else {
    auto epi = [&](const f32x4 (&a4)[4][2], int qm, int qn) {
#pragma unroll
      for (int nr = 0; nr < 2; ++nr) {
        const int col = cb + qn * 128 + wcol + nr * 16 + lrin;
        float bv = 0.0f;
        if (EPI == EPI_QKV || EPI == EPI_F32B) bv = bias[col];
#pragma unroll
        for (int mr = 0; mr < 4; ++mr) {
          const int rowb = rb + qm * 128 + wrow + mr * 16 + lhi * 4;
          const f32x4 v4 = a4[mr][nr];
#pragma unroll
          for (int r = 0; r < 4; ++r) {
            const int row = rowb + r;
            const float v = v4[r];
            if (EPI == EPI_QKV) {
              _Float16* dst = (matid == 0) ? o0 : o1;
              const int cl = col & 1023;
              dst[(long)row * 1024 + cl] = (_Float16)(v + bv);
            } else if (EPI == EPI_SF16) {
              int dd = row - col; if (dd < 0) dd = -dd;
              o0[(long)z * sC + (long)row * N + col] = (_Float16)(v * pwtab[dd]);
            } else if (EPI == EPI_PVO) {
              o0[(long)z * sC + (long)row * N + col] = (_Float16)v;
            } else {  // EPI_F32B
              outF[(long)row * N + col] = v + bv;
            }
          }
        }
      }
    };
    epi(acc00, 0, 0);
    epi(acc01, 0, 1);
    epi(acc11, 1, 1);
    epi(acc10, 1, 0);
  }
}

// ---------------- row softmax over 2048: f16 in -> f32 attn + f16 copy ----------------
__global__ __launch_bounds__(256) void softmax_kernel(
    const _Float16* __restrict__ sbf, float* __restrict__ attn,
    _Float16* __restrict__ abf) {
  const long base = (long)blockIdx.x * S + threadIdx.x * 8;
  const int tid = threadIdx.x;
  const f16x8 sv = *(const f16x8*)(sbf + base);
  float v[8];
  #pragma unroll
  for (int t = 0; t < 8; ++t) v[t] = (float)sv[t];
  float m = fmaxf(fmaxf(fmaxf(v[0], v[1]), fmaxf(v[2], v[3])),
                  fmaxf(fmaxf(v[4], v[5]), fmaxf(v[6], v[7])));
  #pragma unroll
  for (int sh = 1; sh < 64; sh <<= 1) m = fmaxf(m, __shfl_xor(m, sh));
  __shared__ float red[8];
  const int w = tid >> 6;
  if ((tid & 63) == 0) red[w] = m;
  __syncthreads();
  m = fmaxf(fmaxf(red[0], red[1]), fmaxf(red[2], red[3]));
  float e[8];
  #pragma unroll
  for (int t = 0; t < 8; ++t) e[t] = expf(v[t] - m);
  float s8 = ((e[0] + e[1]) + (e[2] + e[3])) + ((e[4] + e[5]) + (e[6] + e[7]));
  #pragma unroll
  for (int sh = 1; sh < 64; sh <<= 1) s8 += __shfl_xor(s8, sh);
  if ((tid & 63) == 0) red[4 + w] = s8;
  __syncthreads();
  const float inv = 1.0f / ((red[4] + red[5]) + (red[6] + red[7]));
  float4 o0 = make_float4(e[0] * inv, e[1] * inv, e[2] * inv, e[3] * inv);
  float4 o1 = make_float4(e[4] * inv, e[5] * inv, e[6] * inv, e[7] * inv);
  *(float4*)(attn + base) = o0;
  *(float4*)(attn + base + 4) = o1;
  f16x8 hb;
  hb[0] = (_Float16)o0.x; hb[1] = (_Float16)o0.y;
  hb[2] = (_Float16)o0.z; hb[3] = (_Float16)o0.w;
  hb[4] = (_Float16)o1.x; hb[5] = (_Float16)o1.y;
  hb[6] = (_Float16)o1.z; hb[7] = (_Float16)o1.w;
  *(f16x8*)(abf + base) = hb;
}

extern "C" void kernel_launch(void* const* d_in, const int* in_sizes, int n_in,
                              void* d_out, int out_size, void* d_ws, size_t ws_size,
                              hipStream_t stream) {
  const float* x   = (const float*)d_in[0];
  const float* pos = (const float*)d_in[1];
  const float* Wq  = (const float*)d_in[2];
  const float* bq  = (const float*)d_in[3];
  const float* Wk  = (const float*)d_in[4];
  const float* bk  = (const float*)d_in[5];
  const float* Wv  = (const float*)d_in[6];
  const float* bv  = (const float*)d_in[7];
  const float* Wo  = (const float*)d_in[8];
  const float* bo  = (const float*)d_in[9];

  float* outp  = (float*)d_out;          // [B,S,D] f32
  float* attnp = outp + BSD;             // [B,S,S] f32 (final attn)

  // workspace layout (~243 MB of ws)
  _Float16* wqkv = (_Float16*)d_ws;              // [3072][1024] f16
  _Float16* woh  = wqkv + 3 * DD;                // [1024][1024] f16
  float*    bcat = (float*)(woh + DD);           // [3072] f32
  float*    pwtab = bcat + 3072;                 // [2048] f32
  _Float16* qh  = (_Float16*)(pwtab + 2048);     // [B*S][D] f16
  _Float16* kh  = qh + BSD;                      // [B*S][D]
  _Float16* vt  = kh + BSD;                      // [B][D][S]
  _Float16* sbf = vt + BSD;                      // [B][S][S] f16 scores
  _Float16* abf = sbf + (long)B * SS;            // [B][S][S] f16 attn
  _Float16* hbf = qh;                            // PV out reuses qh

  _Float16* xph = (_Float16*)attnp;              // xp f16 in attn region of d_out

  dim3 blk(256);
  prep_w_kernel<<<dim3(16, 16), blk, 0, stream>>>(Wq, Wk, Wv, Wo, wqkv, woh);
  prep_misc_kernel<<<dim3(20), blk, 0, stream>>>(bq, bk, bv, bcat, pwtab);
  prep_x_kernel<<<dim3((int)(BSD / 1024)), blk, 0, stream>>>(x, pos, xph);

  dim3 blk5(512);
  // fused QKV projection: [16384,1024] @ [3072,1024]^T
  gemm256_kernel<EPI_QKV><<<dim3(12, 64, 1), blk5, 0, stream>>>(
      xph, wqkv, bcat, nullptr, nullptr, qh, kh, vt, B * S, 3 * D, D, 0, 0, 0);

  // scores (f16, pw-scaled): per-batch [2048,1024] @ [2048,1024]^T
  gemm256_kernel<EPI_SF16><<<dim3(8, 8, B), blk5, 0, stream>>>(
      qh, kh, nullptr, pwtab, nullptr, sbf, nullptr, nullptr, S, S, D, SD, SD, SS);

  softmax_kernel<<<dim3(B * S), blk, 0, stream>>>(sbf, attnp, abf);

  // PV: per-batch [2048,2048] @ [1024,2048]^T
  gemm256_kernel<EPI_PVO><<<dim3(4, 8, B), blk5, 0, stream>>>(
      abf, vt, nullptr, nullptr, nullptr, hbf, nullptr, nullptr, S, D, S, SS, SD, SD);

  // out-proj: [16384,1024] @ [1024,1024]^T + bo -> f32
  gemm256_kernel<EPI_F32B><<<dim3(4, 64, 1), blk5, 0, stream>>>(
      hbf, woh, bo, nullptr, outp, nullptr, nullptr, nullptr, B * S, D, D, 0, 0, 0);
}